// Round 14
// baseline (429.696 us; speedup 1.0000x reference)
//
#include <hip/hip_runtime.h>
#include <stdint.h>

// ---------------- problem constants ----------------
#define SEQ   500
#define BATCH 32
#define DIN   256
#define DM    512
#define NH    8
#define NL    2
#define DF    2048
#define WINSZ 100
#define HD    64          // DM/NH
#define ROWS  (SEQ*BATCH) // 16000
#define MPAD  16128       // 63*256 = 126*128

typedef __bf16 bf16x8 __attribute__((ext_vector_type(8)));
typedef float  f32x4  __attribute__((ext_vector_type(4)));

// ---------------- helpers ----------------
__device__ __forceinline__ unsigned short bfbits(float f) {
    unsigned int u = __builtin_bit_cast(unsigned int, f);
    u = u + 0x7fffu + ((u >> 16) & 1u);           // RNE
    return (unsigned short)(u >> 16);
}
__device__ __forceinline__ unsigned int pack2(float a, float b) {
    return (unsigned int)bfbits(a) | ((unsigned int)bfbits(b) << 16);
}
__device__ __forceinline__ float blo(unsigned int u) { return __builtin_bit_cast(float, u << 16); }
__device__ __forceinline__ float bhi(unsigned int u) { return __builtin_bit_cast(float, u & 0xffff0000u); }

__device__ __forceinline__ void async16(void* lds, const void* g) {
    __builtin_amdgcn_global_load_lds((__attribute__((address_space(1))) void*)(void*)g,
                                     (__attribute__((address_space(3))) void*)(void*)lds,
                                     16, 0, 0);
}

// ---------------- transpose + cast f32[R][C] -> bf16[C][R] ----------------
__global__ __launch_bounds__(256) void tcast_k(const float* __restrict__ src,
                                               unsigned short* __restrict__ dst,
                                               int R, int C) {
    __shared__ float t[32][33];
    int c0 = blockIdx.x * 32, r0 = blockIdx.y * 32;
    int tx = threadIdx.x, ty = threadIdx.y;
#pragma unroll
    for (int k = 0; k < 32; k += 8)
        t[ty + k][tx] = src[(size_t)(r0 + ty + k) * C + c0 + tx];
    __syncthreads();
#pragma unroll
    for (int k = 0; k < 32; k += 8)
        dst[(size_t)(c0 + ty + k) * R + r0 + tx] = bfbits(t[tx][ty + k]);
}

// ---------------- pos-encoding table + qkv bias concat ----------------
__global__ __launch_bounds__(256) void prep_k(const float* __restrict__ bq,
                                              const float* __restrict__ bk,
                                              const float* __restrict__ bv,
                                              float* __restrict__ bias_qkv,
                                              float* __restrict__ pe) {
    int tid = blockIdx.x * 256 + threadIdx.x;
    if (tid < SEQ * DM) {
        int s = tid >> 9, c = tid & 511;
        int p = c >> 1;
        float div = expf(-(float)(2 * p) * (9.210340371976184f / 512.0f)); // ln(10000)/512
        float ang = (float)s * div;
        pe[tid] = (c & 1) ? cosf(ang) : sinf(ang);
    }
    if (tid < NL * 3 * DM) {
        int l = tid / (3 * DM), r = tid % (3 * DM);
        float v = (r < DM) ? bq[l * DM + r]
                : (r < 2 * DM) ? bk[l * DM + r - DM]
                               : bv[l * DM + r - 2 * DM];
        bias_qkv[tid] = v;
    }
}

// ---------------- cast x (f32) -> bf16 ----------------
__global__ __launch_bounds__(256) void xcast_k(const float* __restrict__ x,
                                               unsigned short* __restrict__ xb, int n) {
    int i = (blockIdx.x * 256 + threadIdx.x) * 4;
    if (i < n) {
        float4 v = *(const float4*)&x[i];
        uint2 o; o.x = pack2(v.x, v.y); o.y = pack2(v.z, v.w);
        *(uint2*)&xb[i] = o;
    }
}

// ---------------- gemm4_k: 128x128 tile, BK=64, 2-slot dbuf, counted-vmcnt phases ----
// gemm3's schedule at 128^2 / 256 thr (2x2 waves, wave tile 64x64, MI=4).
// Staging parts (1 load/thread each), needed-order [B0,B1,A0,A2,B2,B3,A1,A3]:
//  A part p covers rows [32p,32p+32): afL (i=0,1, rows wr*64+[0,32)) needs parts 0,2;
//  afH (i=2,3) needs parts 1,3. B part q covers pos [32q,32q+32) <=> j=q.
// Gates (steady state): ph1/ph2/ph3 vmcnt(4); tail vmcnt(4)/(2)/(0). Never drains
// mid-loop. WAR: 2-slot; slot s last read at kt.ph3, kt+1's writes to the other
// slot, kt+2's writes to s are issued after kt+1.ph1's barrier (all waves past
// kt.ph3 reads). Swizzle: A store c^(row&7), B store cs^(lrr&7); reads XOR
// (kk*4+grp)^(lr|ra &7) -> 8 bank-quads, 2 lanes each, conflict-free.
// MODE 1: +bias   MODE 2: relu(+bias)   MODE 3: +bias +posenc (embed)
template <int MODE>
__global__ __launch_bounds__(256, 2)
void gemm4_k(const unsigned short* __restrict__ A,
             const unsigned short* __restrict__ Wt,
             const float* __restrict__ bias,
             unsigned short* __restrict__ outB,
             const float* __restrict__ pe,
             int Mt, int Nt, int K, int N) {
    __shared__ unsigned short LA[2][128 * 64];   // 16 KB/slot
    __shared__ unsigned short LB[2][128 * 64];   // 16 KB/slot

    const int tid = threadIdx.x, lane = tid & 63, wid = tid >> 6;
    const int wr = wid >> 1, wc = wid & 1;
    const int lr = lane & 15, grp = lane >> 4;

    int lin = blockIdx.x;
    int base_m = (lin / (8 * Nt)) * 8;
    int Gc = min(8, Mt - base_m);
    int rem = lin - base_m * Nt;
    int mt = base_m + rem % Gc, nt = rem / Gc;
    const int m0 = mt * 128, n0 = nt * 128;

    const int NKT = K >> 6;

    auto stA = [&](int kt, int part) {
        int slot = kt & 1, k0 = kt << 6;
        int g = part * 256 + tid;                // row = g>>3 in [32p, 32p+32)
        int row = g >> 3, c = g & 7;
        int src = c ^ (row & 7);
        async16(&LA[slot][g * 8], A + (size_t)(m0 + row) * K + k0 + src * 8);
    };
    auto stB = [&](int kt, int part) {
        int slot = kt & 1, k0 = kt << 6;
        int g = part * 256 + tid;                // pos = g>>3; part q <-> j = q
        int pos = g >> 3, cs = g & 7;
        int j = pos >> 5, wcc = (pos >> 4) & 1, lrr = pos & 15;
        int rb = wcc * 64 + lrr * 4 + j;
        int c = cs ^ (lrr & 7);
        async16(&LB[slot][g * 8], Wt + (size_t)(n0 + rb) * K + k0 + c * 8);
    };

    f32x4 acc[4][4] = {};

    // prologue: tile 0, needed-order
    stB(0, 0); stB(0, 1); stA(0, 0); stA(0, 2); stB(0, 2); stB(0, 3); stA(0, 1); stA(0, 3);

    for (int kt = 0; kt < NKT; ++kt) {
        const int slot = kt & 1;
        const bool pf = (kt + 1 < NKT);
        bf16x8 afL[4], afH[4], bf01[4], bf23[4];

        // ---------------- phase 1: bf01 + afL ; prefetch B0,B1 ; MFMA i01 x j01 ----
        asm volatile("s_waitcnt vmcnt(4)" ::: "memory");
        __builtin_amdgcn_s_barrier();
        __builtin_amdgcn_sched_barrier(0);
#pragma unroll
        for (int j = 0; j < 2; ++j)
#pragma unroll
            for (int kk = 0; kk < 2; ++kk) {
                int pos = j * 32 + wc * 16 + lr;
                bf01[j * 2 + kk] = *(const bf16x8*)&LB[slot][pos * 64 + (((kk * 4 + grp) ^ (lr & 7)) << 3)];
            }
#pragma unroll
        for (int i = 0; i < 2; ++i)
#pragma unroll
            for (int kk = 0; kk < 2; ++kk) {
                int ra = wr * 64 + i * 16 + lr;
                afL[i * 2 + kk] = *(const bf16x8*)&LA[slot][ra * 64 + (((kk * 4 + grp) ^ (ra & 7)) << 3)];
            }
        if (pf) { stB(kt + 1, 0); stB(kt + 1, 1); }
        __builtin_amdgcn_s_setprio(1);
#pragma unroll
        for (int i = 0; i < 2; ++i)
#pragma unroll
            for (int j = 0; j < 2; ++j)
#pragma unroll
                for (int kk = 0; kk < 2; ++kk)
                    acc[i][j] = __builtin_amdgcn_mfma_f32_16x16x32_bf16(afL[i * 2 + kk], bf01[j * 2 + kk], acc[i][j], 0, 0, 0);
        __builtin_amdgcn_s_setprio(0);
        __builtin_amdgcn_sched_barrier(0);

        // ---------------- phase 2: bf23 ; prefetch A0,A2 ; MFMA i01 x j23 ----
        if (pf) asm volatile("s_waitcnt vmcnt(4)" ::: "memory");
        else    asm volatile("s_waitcnt vmcnt(2)" ::: "memory");
        __builtin_amdgcn_s_barrier();
        __builtin_amdgcn_sched_barrier(0);
#pragma unroll
        for (int j = 0; j < 2; ++j)
#pragma unroll
            for (int kk = 0; kk < 2; ++kk) {
                int pos = (2 + j) * 32 + wc * 16 + lr;
                bf23[j * 2 + kk] = *(const bf16x8*)&LB[slot][pos * 64 + (((kk * 4 + grp) ^ (lr & 7)) << 3)];
            }
        if (pf) { stA(kt + 1, 0); stA(kt + 1, 2); }
        __builtin_amdgcn_s_setprio(1);
#pragma unroll
        for (int i = 0; i < 2; ++i)
#pragma unroll
            for (int j = 0; j < 2; ++j)
#pragma unroll
                for (int kk = 0; kk < 2; ++kk)
                    acc[i][2 + j] = __builtin_amdgcn_mfma_f32_16x16x32_bf16(afL[i * 2 + kk], bf23[j * 2 + kk], acc[i][2 + j], 0, 0, 0);
        __builtin_amdgcn_s_setprio(0);
        __builtin_amdgcn_sched_barrier(0);

        // ---------------- phase 3: afH ; prefetch B2,B3 ; MFMA i23 x j01 ----
        if (pf) asm volatile("s_waitcnt vmcnt(4)" ::: "memory");
        else    asm volatile("s_waitcnt vmcnt(0)" ::: "memory");
        __builtin_amdgcn_s_barrier();
        __builtin_amdgcn_sched_barrier(0);
#pragma unroll
        for (int i = 0; i < 2; ++i)
#pragma unroll
            for (int kk = 0; kk < 2; ++kk) {
                int ra = wr * 64 + (2 + i) * 16 + lr;
                afH[i * 2 + kk] = *(const bf16x8*)&LA[slot][ra * 64 + (((kk * 4 + grp) ^ (ra & 7)) << 3)];
            }
        if (pf) { stB(kt + 1, 2); stB(kt + 1, 3); }
        __builtin_amdgcn_s_setprio(1);
#pragma unroll
        for (int i = 0; i < 2; ++i)
#pragma unroll
            for (int j = 0; j < 2; ++j)
#pragma unroll
                for (int kk = 0; kk < 2; ++kk)
                    acc[2 + i][j] = __builtin_amdgcn_mfma_f32_16x16x32_bf16(afH[i * 2 + kk], bf01[j * 2 + kk], acc[2 + i][j], 0, 0, 0);
        __builtin_amdgcn_s_setprio(0);
        __builtin_amdgcn_sched_barrier(0);

        // ---------------- phase 4: prefetch A1,A3 ; MFMA i23 x j23 ----
        __builtin_amdgcn_s_barrier();
        __builtin_amdgcn_sched_barrier(0);
        if (pf) { stA(kt + 1, 1); stA(kt + 1, 3); }
        __builtin_amdgcn_s_setprio(1);
#pragma unroll
        for (int i = 0; i < 2; ++i)
#pragma unroll
            for (int j = 0; j < 2; ++j)
#pragma unroll
                for (int kk = 0; kk < 2; ++kk)
                    acc[2 + i][2 + j] = __builtin_amdgcn_mfma_f32_16x16x32_bf16(afH[i * 2 + kk], bf23[j * 2 + kk], acc[2 + i][2 + j], 0, 0, 0);
        __builtin_amdgcn_s_setprio(0);
        __builtin_amdgcn_sched_barrier(0);
    }

    // epilogue: lane owns 4 consecutive cols -> packed dwordx2 stores
    const int colb = n0 + wc * 64 + lr * 4;
    float4 bv4 = *(const float4*)&bias[colb];
#pragma unroll
    for (int i = 0; i < 4; ++i) {
#pragma unroll
        for (int v = 0; v < 4; ++v) {
            int row = m0 + wr * 64 + i * 16 + grp * 4 + v;
            float f0 = acc[i][0][v] + bv4.x;
            float f1 = acc[i][1][v] + bv4.y;
            float f2 = acc[i][2][v] + bv4.z;
            float f3 = acc[i][3][v] + bv4.w;
            if (MODE == 2) {
                f0 = fmaxf(f0, 0.f); f1 = fmaxf(f1, 0.f);
                f2 = fmaxf(f2, 0.f); f3 = fmaxf(f3, 0.f);
            }
            if (MODE == 3) {
                int s = min(row >> 5, SEQ - 1);        // row = s*BATCH + b
                float4 p4 = *(const float4*)&pe[(size_t)s * DM + colb];
                f0 += p4.x; f1 += p4.y; f2 += p4.z; f3 += p4.w;
            }
            uint2 wv; wv.x = pack2(f0, f1); wv.y = pack2(f2, f3);
            *(uint2*)&outB[(size_t)row * N + colb] = wv;
        }
    }
}

// ---------------- gemm3_k: 256x256 tile, BK=64, 2-slot dbuf, counted-vmcnt phases ----
// (validated round 13 on FFN1; see gemm4_k comments for schedule derivation)
template <int MODE>
__global__ __launch_bounds__(512, 2)
void gemm3_k(const unsigned short* __restrict__ A,
             const unsigned short* __restrict__ Wt,
             const float* __restrict__ bias,
             unsigned short* __restrict__ outB,
             int Mt, int Nt, int K, int N) {
    __shared__ unsigned short LA[2][256 * 64];   // 64 KB
    __shared__ unsigned short LB[2][256 * 64];   // 64 KB

    const int tid = threadIdx.x, lane = tid & 63, wid = tid >> 6;
    const int wr = wid >> 2, wc = wid & 3;       // 2 x 4 wave grid
    const int lr = lane & 15, grp = lane >> 4;

    int lin = blockIdx.x;
    int base_m = (lin / (8 * Nt)) * 8;
    int Gc = min(8, Mt - base_m);
    int rem = lin - base_m * Nt;
    int mt = base_m + rem % Gc, nt = rem / Gc;
    const int m0 = mt * 256, n0 = nt * 256;

    const int NKT = K >> 6;

    auto stA = [&](int kt, int part) {
        int slot = kt & 1, k0 = kt << 6;
        int g = part * 512 + tid;
        int row = g >> 3, c = g & 7;
        int src = c ^ (row & 7);
        async16(&LA[slot][g * 8], A + (size_t)(m0 + row) * K + k0 + src * 8);
    };
    auto stB = [&](int kt, int part) {
        int slot = kt & 1, k0 = kt << 6;
        int g = part * 512 + tid;
        int pos = g >> 3, cs = g & 7;
        int j = pos >> 6, wcc = (pos >> 4) & 3, lrr = pos & 15;
        int rb = wcc * 64 + lrr * 4 + j;
        int c = cs ^ (lrr & 7);
        async16(&LB[slot][g * 8], Wt + (size_t)(n0 + rb) * K + k0 + c * 8);
    };

    f32x4 acc[8][4] = {};

    stB(0, 0); stB(0, 1); stA(0, 0); stA(0, 2); stB(0, 2); stB(0, 3); stA(0, 1); stA(0, 3);

    for (int kt = 0; kt < NKT; ++kt) {
        const int slot = kt & 1;
        const bool pf = (kt + 1 < NKT);
        bf16x8 afL[8], afH[8], bf01[4], bf23[4];

        // ---------------- phase 1 ----
        asm volatile("s_waitcnt vmcnt(4)" ::: "memory");
        __builtin_amdgcn_s_barrier();
        __builtin_amdgcn_sched_barrier(0);
#pragma unroll
        for (int j = 0; j < 2; ++j)
#pragma unroll
            for (int kk = 0; kk < 2; ++kk) {
                int pos = j * 64 + wc * 16 + lr;
                bf01[j * 2 + kk] = *(const bf16x8*)&LB[slot][pos * 64 + (((kk * 4 + grp) ^ (lr & 7)) << 3)];
            }
#pragma unroll
        for (int i = 0; i < 4; ++i)
#pragma unroll
            for (int kk = 0; kk < 2; ++kk) {
                int ra = wr * 128 + i * 16 + lr;
                afL[i * 2 + kk] = *(const bf16x8*)&LA[slot][ra * 64 + (((kk * 4 + grp) ^ (ra & 7)) << 3)];
            }
        if (pf) { stB(kt + 1, 0); stB(kt + 1, 1); }
        __builtin_amdgcn_s_setprio(1);
#pragma unroll
        for (int i = 0; i < 4; ++i)
#pragma unroll
            for (int j = 0; j < 2; ++j)
#pragma unroll
                for (int kk = 0; kk < 2; ++kk)
                    acc[i][j] = __builtin_amdgcn_mfma_f32_16x16x32_bf16(afL[i * 2 + kk], bf01[j * 2 + kk], acc[i][j], 0, 0, 0);
        __builtin_amdgcn_s_setprio(0);
        __builtin_amdgcn_sched_barrier(0);

        // ---------------- phase 2 ----
        if (pf) asm volatile("s_waitcnt vmcnt(4)" ::: "memory");
        else    asm volatile("s_waitcnt vmcnt(2)" ::: "memory");
        __builtin_amdgcn_s_barrier();
        __builtin_amdgcn_sched_barrier(0);
#pragma unroll
        for (int j = 0; j < 2; ++j)
#pragma unroll
            for (int kk = 0; kk < 2; ++kk) {
                int pos = (2 + j) * 64 + wc * 16 + lr;
                bf23[j * 2 + kk] = *(const bf16x8*)&LB[slot][pos * 64 + (((kk * 4 + grp) ^ (lr & 7)) << 3)];
            }
        if (pf) { stA(kt + 1, 0); stA(kt + 1, 2); }
        __builtin_amdgcn_s_setprio(1);
#pragma unroll
        for (int i = 0; i < 4; ++i)
#pragma unroll
            for (int j = 0; j < 2; ++j)
#pragma unroll
                for (int kk = 0; kk < 2; ++kk)
                    acc[i][2 + j] = __builtin_amdgcn_mfma_f32_16x16x32_bf16(afL[i * 2 + kk], bf23[j * 2 + kk], acc[i][2 + j], 0, 0, 0);
        __builtin_amdgcn_s_setprio(0);
        __builtin_amdgcn_sched_barrier(0);

        // ---------------- phase 3 ----
        if (pf) asm volatile("s_waitcnt vmcnt(4)" ::: "memory");
        else    asm volatile("s_waitcnt vmcnt(0)" ::: "memory");
        __builtin_amdgcn_s_barrier();
        __builtin_amdgcn_sched_barrier(0);
#pragma unroll
        for (int i = 0; i < 4; ++i)
#pragma unroll
            for (int kk = 0; kk < 2; ++kk) {
                int ra = wr * 128 + (4 + i) * 16 + lr;
                afH[i * 2 + kk] = *(const bf16x8*)&LA[slot][ra * 64 + (((kk * 4 + grp) ^ (ra & 7)) << 3)];
            }
        if (pf) { stB(kt + 1, 2); stB(kt + 1, 3); }
        __builtin_amdgcn_s_setprio(1);
#pragma unroll
        for (int i = 0; i < 4; ++i)
#pragma unroll
            for (int j = 0; j < 2; ++j)
#pragma unroll
                for (int kk = 0; kk < 2; ++kk)
                    acc[4 + i][j] = __builtin_amdgcn_mfma_f32_16x16x32_bf16(afH[i * 2 + kk], bf01[j * 2 + kk], acc[4 + i][j], 0, 0, 0);
        __builtin_amdgcn_s_setprio(0);
        __builtin_amdgcn_sched_barrier(0);

        // ---------------- phase 4 ----
        __builtin_amdgcn_s_barrier();
        __builtin_amdgcn_sched_barrier(0);
        if (pf) { stA(kt + 1, 1); stA(kt + 1, 3); }
        __builtin_amdgcn_s_setprio(1);
#pragma unroll
        for (int i = 0; i < 4; ++i)
#pragma unroll
            for (int j = 0; j < 2; ++j)
#pragma unroll
                for (int kk = 0; kk < 2; ++kk)
                    acc[4 + i][2 + j] = __builtin_amdgcn_mfma_f32_16x16x32_bf16(afH[i * 2 + kk], bf23[j * 2 + kk], acc[4 + i][2 + j], 0, 0, 0);
        __builtin_amdgcn_s_setprio(0);
        __builtin_amdgcn_sched_barrier(0);
    }

    const int colb = n0 + wc * 64 + lr * 4;
    float4 bv4 = *(const float4*)&bias[colb];
#pragma unroll
    for (int i = 0; i < 8; ++i) {
#pragma unroll
        for (int v = 0; v < 4; ++v) {
            int row = m0 + wr * 128 + i * 16 + grp * 4 + v;
            float f0 = acc[i][0][v] + bv4.x;
            float f1 = acc[i][1][v] + bv4.y;
            float f2 = acc[i][2][v] + bv4.z;
            float f3 = acc[i][3][v] + bv4.w;
            if (MODE == 2) {
                f0 = fmaxf(f0, 0.f); f1 = fmaxf(f1, 0.f);
                f2 = fmaxf(f2, 0.f); f3 = fmaxf(f3, 0.f);
            }
            uint2 wv; wv.x = pack2(f0, f1); wv.y = pack2(f2, f3);
            *(uint2*)&outB[(size_t)row * N + colb] = wv;
        }
    }
}

// ---------------- V transpose: qkv V-part -> vT[bh][64][512] (bf16, zero-padded) ----
__global__ __launch_bounds__(256) void vtrans_k(const unsigned short* __restrict__ qkv,
                                                unsigned short* __restrict__ vT) {
    __shared__ unsigned short t[32][72];
    const int s0 = blockIdx.x * 32;
    const int bh = blockIdx.y;
    const int b = bh >> 3, h = bh & 7;
    const int tid = threadIdx.x;
    {
        int sl = tid >> 3;
        int c  = tid & 7;
        int s  = s0 + sl;
        uint4 val = {0, 0, 0, 0};
        if (s < SEQ)
            val = *(const uint4*)&qkv[(size_t)(s * BATCH + b) * (3 * DM) + 2 * DM + h * HD + c * 8];
        *(uint4*)&t[sl][c * 8] = val;
    }
    __syncthreads();
    {
        int d  = tid >> 2;
        int s8 = (tid & 3) * 8;
        unsigned short v[8];
#pragma unroll
        for (int j = 0; j < 8; ++j) v[j] = t[s8 + j][d];
        *(uint4*)&vT[(size_t)(bh * 64 + d) * 512 + s0 + s8] = *(uint4*)v;
    }
}

// ---------------- sliding-window attention, MFMA, QBLK=64, K/V LDS union ----------------
#define QBLK  64
#define NIB   8                  // ceil(500/64)
#define KTIL  11                 // key tiles of 16 -> 176 rows
#define KSTR  72                 // K row stride (shorts)
#define VSTR  200                // V^T row stride (shorts)
#define PSTR  200                // P row stride (shorts)

__global__ __launch_bounds__(256, 3) void attn_k(const unsigned short* __restrict__ qkv,
                                                 const unsigned short* __restrict__ vT,
                                                 unsigned short* __restrict__ ob) {
    __shared__ unsigned short KV[12800];
    __shared__ unsigned short Pl[64 * PSTR];

    const int ib = blockIdx.x & (NIB - 1), bh = blockIdx.x >> 3;
    const int b = bh >> 3, h = bh & 7;
    const int i0 = ib * QBLK;
    const int jbase = max(0, i0 - (WINSZ - 1));
    const int jend  = min(SEQ - 1, i0 + QBLK - 1);
    const int nkeys = jend - jbase + 1;
    const int NT  = (nkeys + 15) >> 4;
    const int NKS = (nkeys + 31) >> 5;
    const int tid = threadIdx.x, lane = tid & 63, w = tid >> 6;
    const int q15 = lane & 15, grp = lane >> 4;

#pragma unroll
    for (int it = 0; it < 6; ++it) {
        int g = it * 256 + tid;
        if (g < 1408) {
            int row = g >> 3, c = g & 7;
            uint4 val = {0, 0, 0, 0};
            if (row < nkeys)
                val = *(const uint4*)&qkv[(size_t)((jbase + row) * BATCH + b) * (3 * DM)
                                          + DM + h * HD + c * 8];
            *(uint4*)&KV[row * KSTR + c * 8] = val;
        }
    }
#pragma unroll
    for (int it = 0; it < 7; ++it) {
        int g = it * 256 + tid;
        if (g < 1600) { uint4 z = {0, 0, 0, 0}; *(uint4*)&Pl[g * 8] = z; }
    }
    uint4 vreg[6];
#pragma unroll
    for (int it = 0; it < 6; ++it) {
        int g = it * 256 + tid;
        int r = g / 24, c = g - r * 24;
        uint4 val = {0, 0, 0, 0};
        if (c * 8 < nkeys && jbase + c * 8 + 8 <= 512)
            val = *(const uint4*)&vT[(size_t)(bh * 64 + r) * 512 + jbase + c * 8];
        vreg[it] = val;
    }
    bf16x8 qav, qbv;
    {
        int iq = min(i0 + w * 16 + q15, SEQ - 1);
        size_t qrow = (size_t)(iq * BATCH + b) * (3 * DM) + h * HD;
        uint4 a = *(const uint4*)&qkv[qrow + grp * 8];
        uint4 c = *(const uint4*)&qkv[qrow + 32 + grp * 8];
        qav = __builtin_bit_cast(bf16x8, a);
        qbv = __builtin_bit_cast(bf16x8, c);
    }
    __syncthreads();

    const int i = i0 + w * 16 + q15;
    float sc[KTIL][4];
#pragma unroll
    for (int t = 0; t < KTIL; ++t) {
        if (t >= NT) continue;
        f32x4 acc = {};
        int row = t * 16 + q15;
        bf16x8 kf0 = *(const bf16x8*)&KV[row * KSTR + grp * 8];
        acc = __builtin_amdgcn_mfma_f32_16x16x32_bf16(kf0, qav, acc, 0, 0, 0);
        bf16x8 kf1 = *(const bf16x8*)&KV[row * KSTR + 32 + grp * 8];
        acc = __builtin_amdgcn_mfma_f32_16x16x32_bf16(kf1, qbv, acc, 0, 0, 0);
#pragma unroll
        for (int v = 0; v < 4; ++v) {
            int key = jbase + t * 16 + grp * 4 + v;
            bool valid = (key <= i) && (key > i - WINSZ);
            sc[t][v] = valid ? acc[v] * 0.125f : -1e30f;
        }
    }
    float m = -1e30f;
#pragma unroll
    for (int t = 0; t < KTIL; ++t) {
        if (t >= NT) continue;
#pragma unroll
        for (int v = 0; v < 4; ++v) m = fmaxf(m, sc[t][v]);
    }
    m = fmaxf(m, __shfl_xor(m, 16));
    m = fmaxf(m, __shfl_xor(m, 32));
    float sum = 0.f;
#pragma unroll
    for (int t = 0; t < KTIL; ++t) {
        if (t >= NT) continue;
#pragma unroll
        for (int v = 0; v < 4; ++v) {
            float p = __expf(sc[t][v] - m);
            sc[t][v] = p;
            sum += p;
        }
    }
    sum += __shfl_xor(sum, 16);
    sum += __shfl_xor(sum, 32);

    __syncthreads();

#pragma unroll
    for (int it = 0; it < 6; ++it) {
        int g = it * 256 + tid;
        int r = g / 24, c = g - r * 24;
        *(uint4*)&KV[r * VSTR + c * 8] = vreg[it];
    }
#pragma unroll
    for (int t = 0; t < KTIL; ++t) {
        if (t >= NT) continue;
        uint2 pk;
        pk.x = pack2(sc[t][0], sc[t][1]);
        pk.y = pack2(sc[t][2], sc[t][3]);
        *(uint2*)&Pl[(w * 16 + q15) * PSTR + t * 16 + grp * 4] = pk;
    }
    __syncthreads();

    f32x4 oacc[4] = {};
#pragma unroll
    for (int ks = 0; ks < 6; ++ks) {
        if (ks >= NKS) continue;
        bf16x8 pf = *(const bf16x8*)&Pl[(w * 16 + q15) * PSTR + ks * 32 + grp * 8];
#pragma unroll
        for (int dt = 0; dt < 4; ++dt) {
            bf16x8 vf = *(const bf16x8*)&KV[(dt * 16 + q15) * VSTR + ks * 32 + grp * 8];
            oacc[dt] = __builtin_amdgcn_mfma_f32_16x16x32_bf16(pf, vf, oacc[dt], 0, 0, 0);
        }
    }

#pragma unroll
    for (int v = 0; v < 4; ++v) {
        float rsv = 1.0f / __shfl(sum, grp * 4 + v);
        int irow = i0 + w * 16 + grp * 4 + v;
        if (irow < SEQ) {
            size_t base = (size_t)(irow * BATCH + b) * DM + h * HD + q15;
#pragma unroll
            for (int dt = 0; dt < 4; ++dt)
                ob[base + dt * 16] = bfbits(oacc[dt][v] * rsv);
        }
    }
}

// ---------------- residual + layernorm (wave per row); bf16 in, bf16 or f32 out ----
template <int FOUT>
__global__ __launch_bounds__(256) void ln_k(const unsigned short* __restrict__ hin,
                                            const unsigned short* __restrict__ yin,
                                            const float* __restrict__ sc,
                                            const float* __restrict__ bi,
                                            unsigned short* __restrict__ hb,
                                            float* __restrict__ fout) {
    int row = blockIdx.x * 4 + (threadIdx.x >> 6);
    int lane = threadIdx.x & 63;
    size_t base = (size_t)row * DM + lane * 8;
    uint4 hw = *(const uint4*)&hin[base];
    uint4 yw = *(const uint4*)&yin[base];
    float x[8] = {blo(hw.x) + blo(yw.x), bhi(hw.x) + bhi(yw.x),
                  blo(hw.y) + blo(yw.y), bhi(hw.y) + bhi(yw.y),
                  blo(hw.z) + blo(yw.z), bhi(hw.z) + bhi(yw.z),
                  blo(hw.w) + blo(yw.w), bhi(hw.w) + bhi(yw.w)};
    float s = 0.f;
#pragma unroll
    for (int k = 0; k < 8; ++k) s += x[k];
#pragma unroll
    for (int off = 32; off; off >>= 1) s += __shfl_xor(s, off);
    float mean = s * (1.f / DM);
    float q = 0.f;
#pragma unroll
    for (int k = 0; k < 8; ++k) { float d = x[k] - mean; q = fmaf(d, d, q); }
#pragma unroll
    for (int off = 32; off; off >>= 1) q += __shfl_xor(q, off);
    float rstd = rsqrtf(q * (1.f / DM) + 1e-5f);
    float4 s0 = *(const float4*)&sc[lane * 8], s1 = *(const float4*)&sc[lane * 8 + 4];
    float4 b0 = *(const float4*)&bi[lane * 8], b1 = *(const float4*)&bi[lane * 8 + 4];
    float o[8];
    o[0] = (x[0] - mean) * rstd * s0.x + b0.x;  o[1] = (x[1] - mean) * rstd * s0.y + b0.y;
    o[2] = (x[2] - mean) * rstd * s0.z + b0.z;  o[3] = (x[3] - mean) * rstd * s0.w + b0.w;
    o[4] = (x[4] - mean) * rstd * s1.x + b1.x;  o[5] = (x[5] - mean) * rstd * s1.y + b1.y;
    o[6] = (x[6] - mean) * rstd * s1.z + b1.z;  o[7] = (x[7] - mean) * rstd * s1.w + b1.w;
    if (FOUT) {
        float4 w0 = {o[0], o[1], o[2], o[3]}, w1 = {o[4], o[5], o[6], o[7]};
        *(float4*)&fout[base] = w0;
        *(float4*)&fout[base + 4] = w1;
    } else {
        uint4 pk = {pack2(o[0], o[1]), pack2(o[2], o[3]), pack2(o[4], o[5]), pack2(o[6], o[7])};
        *(uint4*)&hb[base] = pk;
    }
}

// ---------------- host launch ----------------
extern "C" void kernel_launch(void* const* d_in, const int* in_sizes, int n_in,
                              void* d_out, int out_size, void* d_ws, size_t ws_size,
                              hipStream_t stream) {
    const float* x     = (const float*)d_in[0];
    const float* Wemb  = (const float*)d_in[1];
    const float* bemb  = (const float*)d_in[2];
    const float* Wq    = (const float*)d_in[3];
    const float* bq    = (const float*)d_in[4];
    const float* Wk    = (const float*)d_in[5];
    const float* bk    = (const float*)d_in[6];
    const float* Wv    = (const float*)d_in[7];
    const float* bv    = (const float*)d_in[8];
    const float* Wo    = (const float*)d_in[9];
    const float* bo    = (const float*)d_in[10];
    const float* ln1s  = (const float*)d_in[11];
    const float* ln1b  = (const float*)d_in[12];
    const float* W1    = (const float*)d_in[13];
    const float* b1    = (const float*)d_in[14];
    const float* W2    = (const float*)d_in[15];
    const float* b2    = (const float*)d_in[16];
    const float* ln2s  = (const float*)d_in[17];
    const float* ln2b  = (const float*)d_in[18];

    char* p = (char*)d_ws;
    auto carve = [&](size_t bytes) { char* r = p; p += (bytes + 255) & ~(size_t)255; return r; };

    unsigned short* wt_emb = (unsigned short*)carve((size_t)DM * DIN * 2);
    unsigned short* wt_qkv = (unsigned short*)carve((size_t)NL * 3 * DM * DM * 2);
    unsigned short* wt_o   = (unsigned short*)carve((size_t)NL * DM * DM * 2);
    unsigned short* wt_1   = (unsigned short*)carve((size_t)NL * DF * DM * 2);
    unsigned short* wt_2   = (unsigned short*)carve((size_t)NL * DM * DF * 2);
    float*          biasq  = (float*)carve((size_t)NL * 3 * DM * 4);
    float*          pe     = (float*)carve((size_t)SEQ * DM * 4);
    unsigned short* xb     = (unsigned short*)carve((size_t)MPAD * DIN * 2);
    unsigned short* h      = (unsigned short*)carve((size_t)MPAD * DM * 2);
    unsigned short* ob     = (unsigned short*)carve((size_t)MPAD * DM * 2);
    unsigned short* t0b    = (unsigned short*)carve((size_t)MPAD * DM * 2);
    unsigned short* vT     = (unsigned short*)carve((size_t)BATCH * NH * 64 * 512 * 2 + 1024);
    unsigned short* qkv    = (unsigned short*)carve((size_t)MPAD * DF * 2);
    unsigned short* f1     = qkv;

    dim3 blk256(256);

    tcast_k<<<dim3(DM / 32, DIN / 32), dim3(32, 8), 0, stream>>>(Wemb, wt_emb, DIN, DM);
    for (int l = 0; l < NL; ++l) {
        tcast_k<<<dim3(DM / 32, DM / 32), dim3(32, 8), 0, stream>>>(Wq + (size_t)l * DM * DM, wt_qkv + (size_t)l * 3 * DM * DM, DM, DM);
        tcast_k<<<dim3(DM / 32, DM / 32), dim3(32, 8), 0, stream>>>(Wk + (size_t)l * DM * DM, wt_qkv + (size_t)l * 3 * DM * DM + (size_t)DM * DM, DM, DM);
        tcast_k<<<dim3(DM / 32, DM / 32), dim3(32, 8), 0, stream>>>(Wv + (size_t)l * DM * DM, wt_qkv + (size_t)l * 3 * DM * DM + (size_t)2 * DM * DM, DM, DM);
        tcast_k<<<dim3(DM / 32, DM / 32), dim3(32, 8), 0, stream>>>(Wo + (size_t)l * DM * DM, wt_o + (size_t)l * DM * DM, DM, DM);
        tcast_k<<<dim3(DF / 32, DM / 32), dim3(32, 8), 0, stream>>>(W1 + (size_t)l * DM * DF, wt_1 + (size_t)l * DF * DM, DM, DF);
        tcast_k<<<dim3(DM / 32, DF / 32), dim3(32, 8), 0, stream>>>(W2 + (size_t)l * DF * DM, wt_2 + (size_t)l * DM * DF, DF, DM);
    }
    prep_k<<<dim3((SEQ * DM + 255) / 256), blk256, 0, stream>>>(bq, bk, bv, biasq, pe);
    xcast_k<<<dim3(ROWS * DIN / 4 / 256), blk256, 0, stream>>>(x, xb, ROWS * DIN);

    const int Mt256 = MPAD / 256;   // 63
    const int Mt128 = MPAD / 128;   // 126

    // embedding + posenc -> bf16 h (gemm4, MODE 3)
    gemm4_k<3><<<dim3(Mt128 * 4), blk256, 0, stream>>>(
        xb, wt_emb, bemb, h, pe, Mt128, 4, DIN, DM);

    for (int l = 0; l < NL; ++l) {
        // QKV (gemm4)
        gemm4_k<1><<<dim3(Mt128 * 12), blk256, 0, stream>>>(
            h, wt_qkv + (size_t)l * 3 * DM * DM, biasq + (size_t)l * 3 * DM,
            qkv, nullptr, Mt128, 12, DM, 3 * DM);
        // V transpose
        vtrans_k<<<dim3(16, BATCH * NH), blk256, 0, stream>>>(qkv, vT);
        // attention
        attn_k<<<dim3(BATCH * NH * NIB), blk256, 0, stream>>>(qkv, vT, ob);
        // O-proj -> t0b (gemm4)
        gemm4_k<1><<<dim3(Mt128 * 4), blk256, 0, stream>>>(
            ob, wt_o + (size_t)l * DM * DM, bo + (size_t)l * DM,
            t0b, nullptr, Mt128, 4, DM, DM);
        // LN1
        ln_k<0><<<dim3(ROWS / 4), blk256, 0, stream>>>(h, t0b, ln1s + (size_t)l * DM, ln1b + (size_t)l * DM, h, nullptr);
        // FFN1 -> f1 (relu): gemm3 (validated)
        gemm3_k<2><<<dim3(Mt256 * 8), dim3(512), 0, stream>>>(
            h, wt_1 + (size_t)l * DF * DM, b1 + (size_t)l * DF,
            f1, Mt256, 8, DM, DF);
        // FFN2 -> t0b (gemm4)
        gemm4_k<1><<<dim3(Mt128 * 4), blk256, 0, stream>>>(
            f1, wt_2 + (size_t)l * DM * DF, b2 + (size_t)l * DM,
            t0b, nullptr, Mt128, 4, DF, DM);
        // LN2
        if (l == NL - 1)
            ln_k<1><<<dim3(ROWS / 4), blk256, 0, stream>>>(h, t0b, ln2s + (size_t)l * DM, ln2b + (size_t)l * DM, nullptr, (float*)d_out);
        else
            ln_k<0><<<dim3(ROWS / 4), blk256, 0, stream>>>(h, t0b, ln2s + (size_t)l * DM, ln2b + (size_t)l * DM, h, nullptr);
    }
}

// Round 15
// 394.147 us; speedup vs baseline: 1.0902x; 1.0902x over previous
//
#include <hip/hip_runtime.h>
#include <stdint.h>

// ---------------- problem constants ----------------
#define SEQ   500
#define BATCH 32
#define DIN   256
#define DM    512
#define NH    8
#define NL    2
#define DF    2048
#define WINSZ 100
#define HD    64          // DM/NH
#define ROWS  (SEQ*BATCH) // 16000
#define MPAD  16128       // 63*256 = 126*128

typedef __bf16 bf16x8 __attribute__((ext_vector_type(8)));
typedef float  f32x4  __attribute__((ext_vector_type(4)));

// ---------------- helpers ----------------
__device__ __forceinline__ unsigned short bfbits(float f) {
    unsigned int u = __builtin_bit_cast(unsigned int, f);
    u = u + 0x7fffu + ((u >> 16) & 1u);           // RNE
    return (unsigned short)(u >> 16);
}
__device__ __forceinline__ unsigned int pack2(float a, float b) {
    return (unsigned int)bfbits(a) | ((unsigned int)bfbits(b) << 16);
}
__device__ __forceinline__ float blo(unsigned int u) { return __builtin_bit_cast(float, u << 16); }
__device__ __forceinline__ float bhi(unsigned int u) { return __builtin_bit_cast(float, u & 0xffff0000u); }

__device__ __forceinline__ void async16(void* lds, const void* g) {
    __builtin_amdgcn_global_load_lds((__attribute__((address_space(1))) void*)(void*)g,
                                     (__attribute__((address_space(3))) void*)(void*)lds,
                                     16, 0, 0);
}

// ---------------- merged weight prep: all 13 transposes in ONE launch ----------------
// Flat tile decode: [0,128) Wemb(256x512); [128,2176) 8x 512x512 (Wq/Wk/Wv/Wo x 2L);
// [2176,4224) W1 x2 (512x2048); [4224,6272) W2 x2 (2048x512).
// Per-tile body identical to the old tcast_k (f32[R][C] tile -> bf16[C][R]).
__global__ __launch_bounds__(256) void wprep_k(const float* __restrict__ Wemb,
                                               const float* __restrict__ Wq,
                                               const float* __restrict__ Wk,
                                               const float* __restrict__ Wv,
                                               const float* __restrict__ Wo,
                                               const float* __restrict__ W1,
                                               const float* __restrict__ W2,
                                               unsigned short* __restrict__ wt_emb,
                                               unsigned short* __restrict__ wt_qkv,
                                               unsigned short* __restrict__ wt_o,
                                               unsigned short* __restrict__ wt_1,
                                               unsigned short* __restrict__ wt_2) {
    __shared__ float t[32][33];
    const int tile = blockIdx.x;
    const float* src;
    unsigned short* dst;
    int R, C, bx, by;
    if (tile < 128) {                                   // Wemb: grid (16,8)
        src = Wemb; dst = wt_emb; R = DIN; C = DM;
        bx = tile & 15; by = tile >> 4;
    } else if (tile < 128 + 2048) {                     // 512x512 x8: grid (16,16) each
        int u = tile - 128;
        int m = u >> 8, local = u & 255;
        int l = m >> 2, w = m & 3;
        src = ((w == 0) ? Wq : (w == 1) ? Wk : (w == 2) ? Wv : Wo) + (size_t)l * DM * DM;
        dst = (w < 3) ? wt_qkv + (size_t)l * 3 * DM * DM + (size_t)w * DM * DM
                      : wt_o + (size_t)l * DM * DM;
        R = DM; C = DM;
        bx = local & 15; by = local >> 4;
    } else if (tile < 128 + 2048 + 2048) {              // W1 x2: grid (64,16)
        int u = tile - (128 + 2048);
        int l = u >> 10, local = u & 1023;
        src = W1 + (size_t)l * DM * DF; dst = wt_1 + (size_t)l * DF * DM;
        R = DM; C = DF;
        bx = local & 63; by = local >> 6;
    } else {                                            // W2 x2: grid (16,64)
        int u = tile - (128 + 2048 + 2048);
        int l = u >> 10, local = u & 1023;
        src = W2 + (size_t)l * DF * DM; dst = wt_2 + (size_t)l * DM * DF;
        R = DF; C = DM;
        bx = local & 15; by = local >> 4;
    }
    const int c0 = bx * 32, r0 = by * 32;
    const int tx = threadIdx.x, ty = threadIdx.y;
#pragma unroll
    for (int k = 0; k < 32; k += 8)
        t[ty + k][tx] = src[(size_t)(r0 + ty + k) * C + c0 + tx];
    __syncthreads();
#pragma unroll
    for (int k = 0; k < 32; k += 8)
        dst[(size_t)(c0 + ty + k) * R + r0 + tx] = bfbits(t[tx][ty + k]);
}

// ---------------- pos-encoding table + qkv bias concat ----------------
__global__ __launch_bounds__(256) void prep_k(const float* __restrict__ bq,
                                              const float* __restrict__ bk,
                                              const float* __restrict__ bv,
                                              float* __restrict__ bias_qkv,
                                              float* __restrict__ pe) {
    int tid = blockIdx.x * 256 + threadIdx.x;
    if (tid < SEQ * DM) {
        int s = tid >> 9, c = tid & 511;
        int p = c >> 1;
        float div = expf(-(float)(2 * p) * (9.210340371976184f / 512.0f)); // ln(10000)/512
        float ang = (float)s * div;
        pe[tid] = (c & 1) ? cosf(ang) : sinf(ang);
    }
    if (tid < NL * 3 * DM) {
        int l = tid / (3 * DM), r = tid % (3 * DM);
        float v = (r < DM) ? bq[l * DM + r]
                : (r < 2 * DM) ? bk[l * DM + r - DM]
                               : bv[l * DM + r - 2 * DM];
        bias_qkv[tid] = v;
    }
}

// ---------------- cast x (f32) -> bf16 ----------------
__global__ __launch_bounds__(256) void xcast_k(const float* __restrict__ x,
                                               unsigned short* __restrict__ xb, int n) {
    int i = (blockIdx.x * 256 + threadIdx.x) * 4;
    if (i < n) {
        float4 v = *(const float4*)&x[i];
        uint2 o; o.x = pack2(v.x, v.y); o.y = pack2(v.z, v.w);
        *(uint2*)&xb[i] = o;
    }
}

// ---------------- pipelined MFMA GEMM (counted-vmcnt ring, PHASE-SPLIT K-step) ----
// 256-thr (BM=128): 3-slot ring (48 KB -> 3 blk/CU), PD=2, 2 phases. (proven config)
template <int BM, int BN, int MODE>
__global__ __launch_bounds__(256, 2)
void gemm2_k(const unsigned short* __restrict__ A,
             const unsigned short* __restrict__ Wt,
             const float* __restrict__ bias,
             unsigned short* __restrict__ outB,
             const float* __restrict__ pe,
             int Mt, int Nt, int K, int N) {
    constexpr int NTH = 256;
    constexpr int SLOTS = 3;
    constexpr int PD  = 2;
    constexpr int NWC = BN / 64;               // 2
    constexpr int MI  = 4;
    constexpr int JSH = 5;

    __shared__ unsigned short LA[SLOTS][BM * 32];
    __shared__ unsigned short LB[SLOTS][BN * 32];

    const int tid = threadIdx.x, lane = tid & 63, wid = tid >> 6;
    const int wr = wid / NWC, wc = wid % NWC;
    const int lr = lane & 15, grp = lane >> 4;

    int lin = blockIdx.x;
    int base_m = (lin / (8 * Nt)) * 8;
    int Gc = min(8, Mt - base_m);
    int rem = lin - base_m * Nt;
    int mt = base_m + rem % Gc, nt = rem / Gc;
    const int m0 = mt * BM, n0 = nt * BN;

    const int NKT = K >> 5;

    auto stageA = [&](int kt, int part) {
        int slot = kt % SLOTS, k0 = kt << 5;
        int g = part * NTH + tid;
        int row = g >> 2, c = g & 3;
        int src = c ^ ((row >> 1) & 3);
        async16(&LA[slot][g * 8], A + (size_t)(m0 + row) * K + k0 + src * 8);
    };
    auto stageB = [&](int kt, int part) {
        int slot = kt % SLOTS, k0 = kt << 5;
        int g = part * NTH + tid;
        int pos = g >> 2, cs = g & 3;
        int j   = pos >> JSH;
        int wcc = (pos >> 4) & (NWC - 1);
        int lrr = pos & 15;
        int rb  = wcc * 64 + lrr * 4 + j;
        int c   = cs ^ ((rb >> 3) & 3);
        async16(&LB[slot][g * 8], Wt + (size_t)(n0 + rb) * K + k0 + c * 8);
    };

    f32x4 acc[MI][4] = {};

#pragma unroll
    for (int t = 0; t < PD; ++t) {
        stageA(t, 0); stageA(t, 1); stageB(t, 0); stageB(t, 1);
    }

    for (int kt = 0; kt < NKT; ++kt) {
        const int slot = kt % SLOTS;
        const bool pf = (kt + PD < NKT);
        if (kt + 1 < NKT)      asm volatile("s_waitcnt vmcnt(4)" ::: "memory");
        else                   asm volatile("s_waitcnt vmcnt(0)" ::: "memory");
        __builtin_amdgcn_s_barrier();
        __builtin_amdgcn_sched_barrier(0);

        const int bxor = grp ^ ((lr >> 1) & 3);
        bf16x8 af[MI], bf[4];

        // ---- phase 1 ----
#pragma unroll
        for (int i = 0; i < MI; ++i) {
            int ra = wr * (MI * 16) + i * 16 + lr;
            af[i] = *(const bf16x8*)&LA[slot][ra * 32 + ((grp ^ ((ra >> 1) & 3)) << 3)];
        }
#pragma unroll
        for (int j = 0; j < 2; ++j) {
            int pos = j * (16 * NWC) + wc * 16 + lr;
            bf[j] = *(const bf16x8*)&LB[slot][(pos * 4 + bxor) * 8];
        }
        if (pf) { stageA(kt + PD, 0); stageA(kt + PD, 1); }
        __builtin_amdgcn_s_setprio(1);
#pragma unroll
        for (int i = 0; i < MI; ++i)
#pragma unroll
            for (int j = 0; j < 2; ++j)
                acc[i][j] = __builtin_amdgcn_mfma_f32_16x16x32_bf16(af[i], bf[j], acc[i][j], 0, 0, 0);
        __builtin_amdgcn_s_setprio(0);
        __builtin_amdgcn_s_barrier();
        __builtin_amdgcn_sched_barrier(0);

        // ---- phase 2 ----
#pragma unroll
        for (int j = 2; j < 4; ++j) {
            int pos = j * (16 * NWC) + wc * 16 + lr;
            bf[j] = *(const bf16x8*)&LB[slot][(pos * 4 + bxor) * 8];
        }
        if (pf) { stageB(kt + PD, 0); stageB(kt + PD, 1); }
        __builtin_amdgcn_s_setprio(1);
#pragma unroll
        for (int i = 0; i < MI; ++i)
#pragma unroll
            for (int j = 2; j < 4; ++j)
                acc[i][j] = __builtin_amdgcn_mfma_f32_16x16x32_bf16(af[i], bf[j], acc[i][j], 0, 0, 0);
        __builtin_amdgcn_s_setprio(0);
        __builtin_amdgcn_s_barrier();
        __builtin_amdgcn_sched_barrier(0);
    }

    const int colb = n0 + wc * 64 + lr * 4;
    float4 bv4 = *(const float4*)&bias[colb];
#pragma unroll
    for (int i = 0; i < MI; ++i) {
#pragma unroll
        for (int v = 0; v < 4; ++v) {
            int row = m0 + wr * (MI * 16) + i * 16 + grp * 4 + v;
            float f0 = acc[i][0][v] + bv4.x;
            float f1 = acc[i][1][v] + bv4.y;
            float f2 = acc[i][2][v] + bv4.z;
            float f3 = acc[i][3][v] + bv4.w;
            if (MODE == 2) {
                f0 = fmaxf(f0, 0.f); f1 = fmaxf(f1, 0.f);
                f2 = fmaxf(f2, 0.f); f3 = fmaxf(f3, 0.f);
            }
            if (MODE == 3) {
                int s = min(row >> 5, SEQ - 1);
                float4 p4 = *(const float4*)&pe[(size_t)s * DM + colb];
                f0 += p4.x; f1 += p4.y; f2 += p4.z; f3 += p4.w;
            }
            uint2 wv; wv.x = pack2(f0, f1); wv.y = pack2(f2, f3);
            *(uint2*)&outB[(size_t)row * N + colb] = wv;
        }
    }
}

// ---------------- gemm3_k: 256x256 tile, BK=64, 2-slot dbuf, counted-vmcnt phases ----
// (validated round 13 on FFN1) Staging parts needed-order [B0,B1,A0,A2,B2,B3,A1,A3];
// steady-state gates vmcnt(4)/(4)/(4), tail (4)/(2)/(0). WAR: 2-slot, see round-13 audit.
template <int MODE>
__global__ __launch_bounds__(512, 2)
void gemm3_k(const unsigned short* __restrict__ A,
             const unsigned short* __restrict__ Wt,
             const float* __restrict__ bias,
             unsigned short* __restrict__ outB,
             int Mt, int Nt, int K, int N) {
    __shared__ unsigned short LA[2][256 * 64];   // 64 KB
    __shared__ unsigned short LB[2][256 * 64];   // 64 KB

    const int tid = threadIdx.x, lane = tid & 63, wid = tid >> 6;
    const int wr = wid >> 2, wc = wid & 3;       // 2 x 4 wave grid
    const int lr = lane & 15, grp = lane >> 4;

    int lin = blockIdx.x;
    int base_m = (lin / (8 * Nt)) * 8;
    int Gc = min(8, Mt - base_m);
    int rem = lin - base_m * Nt;
    int mt = base_m + rem % Gc, nt = rem / Gc;
    const int m0 = mt * 256, n0 = nt * 256;

    const int NKT = K >> 6;

    auto stA = [&](int kt, int part) {
        int slot = kt & 1, k0 = kt << 6;
        int g = part * 512 + tid;
        int row = g >> 3, c = g & 7;
        int src = c ^ (row & 7);
        async16(&LA[slot][g * 8], A + (size_t)(m0 + row) * K + k0 + src * 8);
    };
    auto stB = [&](int kt, int part) {
        int slot = kt & 1, k0 = kt << 6;
        int g = part * 512 + tid;
        int pos = g >> 3, cs = g & 7;
        int j = pos >> 6, wcc = (pos >> 4) & 3, lrr = pos & 15;
        int rb = wcc * 64 + lrr * 4 + j;
        int c = cs ^ (lrr & 7);
        async16(&LB[slot][g * 8], Wt + (size_t)(n0 + rb) * K + k0 + c * 8);
    };

    f32x4 acc[8][4] = {};

    stB(0, 0); stB(0, 1); stA(0, 0); stA(0, 2); stB(0, 2); stB(0, 3); stA(0, 1); stA(0, 3);

    for (int kt = 0; kt < NKT; ++kt) {
        const int slot = kt & 1;
        const bool pf = (kt + 1 < NKT);
        bf16x8 afL[8], afH[8], bf01[4], bf23[4];

        // ---------------- phase 1 ----
        asm volatile("s_waitcnt vmcnt(4)" ::: "memory");
        __builtin_amdgcn_s_barrier();
        __builtin_amdgcn_sched_barrier(0);
#pragma unroll
        for (int j = 0; j < 2; ++j)
#pragma unroll
            for (int kk = 0; kk < 2; ++kk) {
                int pos = j * 64 + wc * 16 + lr;
                bf01[j * 2 + kk] = *(const bf16x8*)&LB[slot][pos * 64 + (((kk * 4 + grp) ^ (lr & 7)) << 3)];
            }
#pragma unroll
        for (int i = 0; i < 4; ++i)
#pragma unroll
            for (int kk = 0; kk < 2; ++kk) {
                int ra = wr * 128 + i * 16 + lr;
                afL[i * 2 + kk] = *(const bf16x8*)&LA[slot][ra * 64 + (((kk * 4 + grp) ^ (ra & 7)) << 3)];
            }
        if (pf) { stB(kt + 1, 0); stB(kt + 1, 1); }
        __builtin_amdgcn_s_setprio(1);
#pragma unroll
        for (int i = 0; i < 4; ++i)
#pragma unroll
            for (int j = 0; j < 2; ++j)
#pragma unroll
                for (int kk = 0; kk < 2; ++kk)
                    acc[i][j] = __builtin_amdgcn_mfma_f32_16x16x32_bf16(afL[i * 2 + kk], bf01[j * 2 + kk], acc[i][j], 0, 0, 0);
        __builtin_amdgcn_s_setprio(0);
        __builtin_amdgcn_sched_barrier(0);

        // ---------------- phase 2 ----
        if (pf) asm volatile("s_waitcnt vmcnt(4)" ::: "memory");
        else    asm volatile("s_waitcnt vmcnt(2)" ::: "memory");
        __builtin_amdgcn_s_barrier();
        __builtin_amdgcn_sched_barrier(0);
#pragma unroll
        for (int j = 0; j < 2; ++j)
#pragma unroll
            for (int kk = 0; kk < 2; ++kk) {
                int pos = (2 + j) * 64 + wc * 16 + lr;
                bf23[j * 2 + kk] = *(const bf16x8*)&LB[slot][pos * 64 + (((kk * 4 + grp) ^ (lr & 7)) << 3)];
            }
        if (pf) { stA(kt + 1, 0); stA(kt + 1, 2); }
        __builtin_amdgcn_s_setprio(1);
#pragma unroll
        for (int i = 0; i < 4; ++i)
#pragma unroll
            for (int j = 0; j < 2; ++j)
#pragma unroll
                for (int kk = 0; kk < 2; ++kk)
                    acc[i][2 + j] = __builtin_amdgcn_mfma_f32_16x16x32_bf16(afL[i * 2 + kk], bf23[j * 2 + kk], acc[i][2 + j], 0, 0, 0);
        __builtin_amdgcn_s_setprio(0);
        __builtin_amdgcn_sched_barrier(0);

        // ---------------- phase 3 ----
        if (pf) asm volatile("s_waitcnt vmcnt(4)" ::: "memory");
        else    asm volatile("s_waitcnt vmcnt(0)" ::: "memory");
        __builtin_amdgcn_s_barrier();
        __builtin_amdgcn_sched_barrier(0);
#pragma unroll
        for (int i = 0; i < 4; ++i)
#pragma unroll
            for (int kk = 0; kk < 2; ++kk) {
                int ra = wr * 128 + (4 + i) * 16 + lr;
                afH[i * 2 + kk] = *(const bf16x8*)&LA[slot][ra * 64 + (((kk * 4 + grp) ^ (ra & 7)) << 3)];
            }
        if (pf) { stB(kt + 1, 2); stB(kt + 1, 3); }
        __builtin_amdgcn_s_setprio(1);
#pragma unroll
        for (int i = 0; i < 4; ++i)
#pragma unroll
            for (int j = 0; j < 2; ++j)
#pragma unroll
                for (int kk = 0; kk < 2; ++kk)
                    acc[4 + i][j] = __builtin_amdgcn_mfma_f32_16x16x32_bf16(afH[i * 2 + kk], bf01[j * 2 + kk], acc[4 + i][j], 0, 0, 0);
        __builtin_amdgcn_s_setprio(0);
        __builtin_amdgcn_sched_barrier(0);

        // ---------------- phase 4 ----
        __builtin_amdgcn_s_barrier();
        __builtin_amdgcn_sched_barrier(0);
        if (pf) { stA(kt + 1, 1); stA(kt + 1, 3); }
        __builtin_amdgcn_s_setprio(1);
#pragma unroll
        for (int i = 0; i < 4; ++i)
#pragma unroll
            for (int j = 0; j < 2; ++j)
#pragma unroll
                for (int kk = 0; kk < 2; ++kk)
                    acc[4 + i][2 + j] = __builtin_amdgcn_mfma_f32_16x16x32_bf16(afH[i * 2 + kk], bf23[j * 2 + kk], acc[4 + i][2 + j], 0, 0, 0);
        __builtin_amdgcn_s_setprio(0);
        __builtin_amdgcn_sched_barrier(0);
    }

    const int colb = n0 + wc * 64 + lr * 4;
    float4 bv4 = *(const float4*)&bias[colb];
#pragma unroll
    for (int i = 0; i < 8; ++i) {
#pragma unroll
        for (int v = 0; v < 4; ++v) {
            int row = m0 + wr * 128 + i * 16 + grp * 4 + v;
            float f0 = acc[i][0][v] + bv4.x;
            float f1 = acc[i][1][v] + bv4.y;
            float f2 = acc[i][2][v] + bv4.z;
            float f3 = acc[i][3][v] + bv4.w;
            if (MODE == 2) {
                f0 = fmaxf(f0, 0.f); f1 = fmaxf(f1, 0.f);
                f2 = fmaxf(f2, 0.f); f3 = fmaxf(f3, 0.f);
            }
            uint2 wv; wv.x = pack2(f0, f1); wv.y = pack2(f2, f3);
            *(uint2*)&outB[(size_t)row * N + colb] = wv;
        }
    }
}

// ---------------- V transpose: qkv V-part -> vT[bh][64][512] (bf16, zero-padded) ----
__global__ __launch_bounds__(256) void vtrans_k(const unsigned short* __restrict__ qkv,
                                                unsigned short* __restrict__ vT) {
    __shared__ unsigned short t[32][72];
    const int s0 = blockIdx.x * 32;
    const int bh = blockIdx.y;
    const int b = bh >> 3, h = bh & 7;
    const int tid = threadIdx.x;
    {
        int sl = tid >> 3;
        int c  = tid & 7;
        int s  = s0 + sl;
        uint4 val = {0, 0, 0, 0};
        if (s < SEQ)
            val = *(const uint4*)&qkv[(size_t)(s * BATCH + b) * (3 * DM) + 2 * DM + h * HD + c * 8];
        *(uint4*)&t[sl][c * 8] = val;
    }
    __syncthreads();
    {
        int d  = tid >> 2;
        int s8 = (tid & 3) * 8;
        unsigned short v[8];
#pragma unroll
        for (int j = 0; j < 8; ++j) v[j] = t[s8 + j][d];
        *(uint4*)&vT[(size_t)(bh * 64 + d) * 512 + s0 + s8] = *(uint4*)v;
    }
}

// ---------------- sliding-window attention, MFMA, QBLK=64, K/V LDS union ----------------
#define QBLK  64
#define NIB   8                  // ceil(500/64)
#define KTIL  11                 // key tiles of 16 -> 176 rows
#define KSTR  72                 // K row stride (shorts)
#define VSTR  200                // V^T row stride (shorts)
#define PSTR  200                // P row stride (shorts)

__global__ __launch_bounds__(256, 3) void attn_k(const unsigned short* __restrict__ qkv,
                                                 const unsigned short* __restrict__ vT,
                                                 unsigned short* __restrict__ ob) {
    __shared__ unsigned short KV[12800];
    __shared__ unsigned short Pl[64 * PSTR];

    const int ib = blockIdx.x & (NIB - 1), bh = blockIdx.x >> 3;
    const int b = bh >> 3, h = bh & 7;
    const int i0 = ib * QBLK;
    const int jbase = max(0, i0 - (WINSZ - 1));
    const int jend  = min(SEQ - 1, i0 + QBLK - 1);
    const int nkeys = jend - jbase + 1;
    const int NT  = (nkeys + 15) >> 4;
    const int NKS = (nkeys + 31) >> 5;
    const int tid = threadIdx.x, lane = tid & 63, w = tid >> 6;
    const int q15 = lane & 15, grp = lane >> 4;

#pragma unroll
    for (int it = 0; it < 6; ++it) {
        int g = it * 256 + tid;
        if (g < 1408) {
            int row = g >> 3, c = g & 7;
            uint4 val = {0, 0, 0, 0};
            if (row < nkeys)
                val = *(const uint4*)&qkv[(size_t)((jbase + row) * BATCH + b) * (3 * DM)
                                          + DM + h * HD + c * 8];
            *(uint4*)&KV[row * KSTR + c * 8] = val;
        }
    }
#pragma unroll
    for (int it = 0; it < 7; ++it) {
        int g = it * 256 + tid;
        if (g < 1600) { uint4 z = {0, 0, 0, 0}; *(uint4*)&Pl[g * 8] = z; }
    }
    uint4 vreg[6];
#pragma unroll
    for (int it = 0; it < 6; ++it) {
        int g = it * 256 + tid;
        int r = g / 24, c = g - r * 24;
        uint4 val = {0, 0, 0, 0};
        if (c * 8 < nkeys && jbase + c * 8 + 8 <= 512)
            val = *(const uint4*)&vT[(size_t)(bh * 64 + r) * 512 + jbase + c * 8];
        vreg[it] = val;
    }
    bf16x8 qav, qbv;
    {
        int iq = min(i0 + w * 16 + q15, SEQ - 1);
        size_t qrow = (size_t)(iq * BATCH + b) * (3 * DM) + h * HD;
        uint4 a = *(const uint4*)&qkv[qrow + grp * 8];
        uint4 c = *(const uint4*)&qkv[qrow + 32 + grp * 8];
        qav = __builtin_bit_cast(bf16x8, a);
        qbv = __builtin_bit_cast(bf16x8, c);
    }
    __syncthreads();

    const int i = i0 + w * 16 + q15;
    float sc[KTIL][4];
#pragma unroll
    for (int t = 0; t < KTIL; ++t) {
        if (t >= NT) continue;
        f32x4 acc = {};
        int row = t * 16 + q15;
        bf16x8 kf0 = *(const bf16x8*)&KV[row * KSTR + grp * 8];
        acc = __builtin_amdgcn_mfma_f32_16x16x32_bf16(kf0, qav, acc, 0, 0, 0);
        bf16x8 kf1 = *(const bf16x8*)&KV[row * KSTR + 32 + grp * 8];
        acc = __builtin_amdgcn_mfma_f32_16x16x32_bf16(kf1, qbv, acc, 0, 0, 0);
#pragma unroll
        for (int v = 0; v < 4; ++v) {
            int key = jbase + t * 16 + grp * 4 + v;
            bool valid = (key <= i) && (key > i - WINSZ);
            sc[t][v] = valid ? acc[v] * 0.125f : -1e30f;
        }
    }
    float m = -1e30f;
#pragma unroll
    for (int t = 0; t < KTIL; ++t) {
        if (t >= NT) continue;
#pragma unroll
        for (int v = 0; v < 4; ++v) m = fmaxf(m, sc[t][v]);
    }
    m = fmaxf(m, __shfl_xor(m, 16));
    m = fmaxf(m, __shfl_xor(m, 32));
    float sum = 0.f;
#pragma unroll
    for (int t = 0; t < KTIL; ++t) {
        if (t >= NT) continue;
#pragma unroll
        for (int v = 0; v < 4; ++v) {
            float p = __expf(sc[t][v] - m);
            sc[t][v] = p;
            sum += p;
        }
    }
    sum += __shfl_xor(sum, 16);
    sum += __shfl_xor(sum, 32);

    __syncthreads();

#pragma unroll
    for (int it = 0; it < 6; ++it) {
        int g = it * 256 + tid;
        int r = g / 24, c = g - r * 24;
        *(uint4*)&KV[r * VSTR + c * 8] = vreg[it];
    }
#pragma unroll
    for (int t = 0; t < KTIL; ++t) {
        if (t >= NT) continue;
        uint2 pk;
        pk.x = pack2(sc[t][0], sc[t][1]);
        pk.y = pack2(sc[t][2], sc[t][3]);
        *(uint2*)&Pl[(w * 16 + q15) * PSTR + t * 16 + grp * 4] = pk;
    }
    __syncthreads();

    f32x4 oacc[4] = {};
#pragma unroll
    for (int ks = 0; ks < 6; ++ks) {
        if (ks >= NKS) continue;
        bf16x8 pf = *(const bf16x8*)&Pl[(w * 16 + q15) * PSTR + ks * 32 + grp * 8];
#pragma unroll
        for (int dt = 0; dt < 4; ++dt) {
            bf16x8 vf = *(const bf16x8*)&KV[(dt * 16 + q15) * VSTR + ks * 32 + grp * 8];
            oacc[dt] = __builtin_amdgcn_mfma_f32_16x16x32_bf16(pf, vf, oacc[dt], 0, 0, 0);
        }
    }

#pragma unroll
    for (int v = 0; v < 4; ++v) {
        float rsv = 1.0f / __shfl(sum, grp * 4 + v);
        int irow = i0 + w * 16 + grp * 4 + v;
        if (irow < SEQ) {
            size_t base = (size_t)(irow * BATCH + b) * DM + h * HD + q15;
#pragma unroll
            for (int dt = 0; dt < 4; ++dt)
                ob[base + dt * 16] = bfbits(oacc[dt][v] * rsv);
        }
    }
}

// ---------------- residual + layernorm (wave per row); bf16 in, bf16 or f32 out ----
template <int FOUT>
__global__ __launch_bounds__(256) void ln_k(const unsigned short* __restrict__ hin,
                                            const unsigned short* __restrict__ yin,
                                            const float* __restrict__ sc,
                                            const float* __restrict__ bi,
                                            unsigned short* __restrict__ hb,
                                            float* __restrict__ fout) {
    int row = blockIdx.x * 4 + (threadIdx.x >> 6);
    int lane = threadIdx.x & 63;
    size_t base = (size_t)row * DM + lane * 8;
    uint4 hw = *(const uint4*)&hin[base];
    uint4 yw = *(const uint4*)&yin[base];
    float x[8] = {blo(hw.x) + blo(yw.x), bhi(hw.x) + bhi(yw.x),
                  blo(hw.y) + blo(yw.y), bhi(hw.y) + bhi(yw.y),
                  blo(hw.z) + blo(yw.z), bhi(hw.z) + bhi(yw.z),
                  blo(hw.w) + blo(yw.w), bhi(hw.w) + bhi(yw.w)};
    float s = 0.f;
#pragma unroll
    for (int k = 0; k < 8; ++k) s += x[k];
#pragma unroll
    for (int off = 32; off; off >>= 1) s += __shfl_xor(s, off);
    float mean = s * (1.f / DM);
    float q = 0.f;
#pragma unroll
    for (int k = 0; k < 8; ++k) { float d = x[k] - mean; q = fmaf(d, d, q); }
#pragma unroll
    for (int off = 32; off; off >>= 1) q += __shfl_xor(q, off);
    float rstd = rsqrtf(q * (1.f / DM) + 1e-5f);
    float4 s0 = *(const float4*)&sc[lane * 8], s1 = *(const float4*)&sc[lane * 8 + 4];
    float4 b0 = *(const float4*)&bi[lane * 8], b1 = *(const float4*)&bi[lane * 8 + 4];
    float o[8];
    o[0] = (x[0] - mean) * rstd * s0.x + b0.x;  o[1] = (x[1] - mean) * rstd * s0.y + b0.y;
    o[2] = (x[2] - mean) * rstd * s0.z + b0.z;  o[3] = (x[3] - mean) * rstd * s0.w + b0.w;
    o[4] = (x[4] - mean) * rstd * s1.x + b1.x;  o[5] = (x[5] - mean) * rstd * s1.y + b1.y;
    o[6] = (x[6] - mean) * rstd * s1.z + b1.z;  o[7] = (x[7] - mean) * rstd * s1.w + b1.w;
    if (FOUT) {
        float4 w0 = {o[0], o[1], o[2], o[3]}, w1 = {o[4], o[5], o[6], o[7]};
        *(float4*)&fout[base] = w0;
        *(float4*)&fout[base + 4] = w1;
    } else {
        uint4 pk = {pack2(o[0], o[1]), pack2(o[2], o[3]), pack2(o[4], o[5]), pack2(o[6], o[7])};
        *(uint4*)&hb[base] = pk;
    }
}

// ---------------- host launch ----------------
extern "C" void kernel_launch(void* const* d_in, const int* in_sizes, int n_in,
                              void* d_out, int out_size, void* d_ws, size_t ws_size,
                              hipStream_t stream) {
    const float* x     = (const float*)d_in[0];
    const float* Wemb  = (const float*)d_in[1];
    const float* bemb  = (const float*)d_in[2];
    const float* Wq    = (const float*)d_in[3];
    const float* bq    = (const float*)d_in[4];
    const float* Wk    = (const float*)d_in[5];
    const float* bk    = (const float*)d_in[6];
    const float* Wv    = (const float*)d_in[7];
    const float* bv    = (const float*)d_in[8];
    const float* Wo    = (const float*)d_in[9];
    const float* bo    = (const float*)d_in[10];
    const float* ln1s  = (const float*)d_in[11];
    const float* ln1b  = (const float*)d_in[12];
    const float* W1    = (const float*)d_in[13];
    const float* b1    = (const float*)d_in[14];
    const float* W2    = (const float*)d_in[15];
    const float* b2    = (const float*)d_in[16];
    const float* ln2s  = (const float*)d_in[17];
    const float* ln2b  = (const float*)d_in[18];

    char* p = (char*)d_ws;
    auto carve = [&](size_t bytes) { char* r = p; p += (bytes + 255) & ~(size_t)255; return r; };

    unsigned short* wt_emb = (unsigned short*)carve((size_t)DM * DIN * 2);
    unsigned short* wt_qkv = (unsigned short*)carve((size_t)NL * 3 * DM * DM * 2);
    unsigned short* wt_o   = (unsigned short*)carve((size_t)NL * DM * DM * 2);
    unsigned short* wt_1   = (unsigned short*)carve((size_t)NL * DF * DM * 2);
    unsigned short* wt_2   = (unsigned short*)carve((size_t)NL * DM * DF * 2);
    float*          biasq  = (float*)carve((size_t)NL * 3 * DM * 4);
    float*          pe     = (float*)carve((size_t)SEQ * DM * 4);
    unsigned short* xb     = (unsigned short*)carve((size_t)MPAD * DIN * 2);
    unsigned short* h      = (unsigned short*)carve((size_t)MPAD * DM * 2);
    unsigned short* ob     = (unsigned short*)carve((size_t)MPAD * DM * 2);
    unsigned short* t0b    = (unsigned short*)carve((size_t)MPAD * DM * 2);
    unsigned short* vT     = (unsigned short*)carve((size_t)BATCH * NH * 64 * 512 * 2 + 1024);
    unsigned short* qkv    = (unsigned short*)carve((size_t)MPAD * DF * 2);
    unsigned short* f1     = qkv;

    dim3 blk256(256);

    // ALL weight transposes in one launch (6272 tiles)
    wprep_k<<<dim3(6272), dim3(32, 8), 0, stream>>>(Wemb, Wq, Wk, Wv, Wo, W1, W2,
                                                    wt_emb, wt_qkv, wt_o, wt_1, wt_2);
    prep_k<<<dim3((SEQ * DM + 255) / 256), blk256, 0, stream>>>(bq, bk, bv, biasq, pe);
    xcast_k<<<dim3(ROWS * DIN / 4 / 256), blk256, 0, stream>>>(x, xb, ROWS * DIN);

    const int Mt256 = MPAD / 256;   // 63
    const int Mt128 = MPAD / 128;   // 126

    // embedding + posenc -> bf16 h (gemm2, MODE 3)
    gemm2_k<128, 128, 3><<<dim3(Mt128 * 4), blk256, 0, stream>>>(
        xb, wt_emb, bemb, h, pe, Mt128, 4, DIN, DM);

    for (int l = 0; l < NL; ++l) {
        // QKV (gemm2, 1512 blocks, 3 blk/CU)
        gemm2_k<128, 128, 1><<<dim3(Mt128 * 12), blk256, 0, stream>>>(
            h, wt_qkv + (size_t)l * 3 * DM * DM, biasq + (size_t)l * 3 * DM,
            qkv, nullptr, Mt128, 12, DM, 3 * DM);
        // V transpose
        vtrans_k<<<dim3(16, BATCH * NH), blk256, 0, stream>>>(qkv, vT);
        // attention
        attn_k<<<dim3(BATCH * NH * NIB), blk256, 0, stream>>>(qkv, vT, ob);
        // O-proj -> t0b (gemm2)
        gemm2_k<128, 128, 1><<<dim3(Mt128 * 4), blk256, 0, stream>>>(
            ob, wt_o + (size_t)l * DM * DM, bo + (size_t)l * DM,
            t0b, nullptr, Mt128, 4, DM, DM);
        // LN1
        ln_k<0><<<dim3(ROWS / 4), blk256, 0, stream>>>(h, t0b, ln1s + (size_t)l * DM, ln1b + (size_t)l * DM, h, nullptr);
        // FFN1 -> f1 (relu): gemm3 (validated)
        gemm3_k<2><<<dim3(Mt256 * 8), dim3(512), 0, stream>>>(
            h, wt_1 + (size_t)l * DF * DM, b1 + (size_t)l * DF,
            f1, Mt256, 8, DM, DF);
        // FFN2 -> t0b (gemm2)
        gemm2_k<128, 128, 1><<<dim3(Mt128 * 4), blk256, 0, stream>>>(
            f1, wt_2 + (size_t)l * DM * DF, b2 + (size_t)l * DM,
            t0b, nullptr, Mt128, 4, DF, DM);
        // LN2
        if (l == NL - 1)
            ln_k<1><<<dim3(ROWS / 4), blk256, 0, stream>>>(h, t0b, ln2s + (size_t)l * DM, ln2b + (size_t)l * DM, nullptr, (float*)d_out);
        else
            ln_k<0><<<dim3(ROWS / 4), blk256, 0, stream>>>(h, t0b, ln2s + (size_t)l * DM, ln2b + (size_t)l * DM, h, nullptr);
    }
}

// Round 16
// 392.784 us; speedup vs baseline: 1.0940x; 1.0035x over previous
//
#include <hip/hip_runtime.h>
#include <stdint.h>

// ---------------- problem constants ----------------
#define SEQ   500
#define BATCH 32
#define DIN   256
#define DM    512
#define NH    8
#define NL    2
#define DF    2048
#define WINSZ 100
#define HD    64          // DM/NH
#define ROWS  (SEQ*BATCH) // 16000
#define MPAD  16128       // 63*256 = 126*128

typedef __bf16 bf16x8 __attribute__((ext_vector_type(8)));
typedef float  f32x4  __attribute__((ext_vector_type(4)));

// ---------------- helpers ----------------
__device__ __forceinline__ unsigned short bfbits(float f) {
    unsigned int u = __builtin_bit_cast(unsigned int, f);
    u = u + 0x7fffu + ((u >> 16) & 1u);           // RNE
    return (unsigned short)(u >> 16);
}
__device__ __forceinline__ unsigned int pack2(float a, float b) {
    return (unsigned int)bfbits(a) | ((unsigned int)bfbits(b) << 16);
}
__device__ __forceinline__ float blo(unsigned int u) { return __builtin_bit_cast(float, u << 16); }
__device__ __forceinline__ float bhi(unsigned int u) { return __builtin_bit_cast(float, u & 0xffff0000u); }

__device__ __forceinline__ void async16(void* lds, const void* g) {
    __builtin_amdgcn_global_load_lds((__attribute__((address_space(1))) void*)(void*)g,
                                     (__attribute__((address_space(3))) void*)(void*)lds,
                                     16, 0, 0);
}

// ---------------- merged weight prep: all 13 transposes in ONE launch ----------------
__global__ __launch_bounds__(256) void wprep_k(const float* __restrict__ Wemb,
                                               const float* __restrict__ Wq,
                                               const float* __restrict__ Wk,
                                               const float* __restrict__ Wv,
                                               const float* __restrict__ Wo,
                                               const float* __restrict__ W1,
                                               const float* __restrict__ W2,
                                               unsigned short* __restrict__ wt_emb,
                                               unsigned short* __restrict__ wt_qkv,
                                               unsigned short* __restrict__ wt_o,
                                               unsigned short* __restrict__ wt_1,
                                               unsigned short* __restrict__ wt_2) {
    __shared__ float t[32][33];
    const int tile = blockIdx.x;
    const float* src;
    unsigned short* dst;
    int R, C, bx, by;
    if (tile < 128) {                                   // Wemb: grid (16,8)
        src = Wemb; dst = wt_emb; R = DIN; C = DM;
        bx = tile & 15; by = tile >> 4;
    } else if (tile < 128 + 2048) {                     // 512x512 x8: grid (16,16) each
        int u = tile - 128;
        int m = u >> 8, local = u & 255;
        int l = m >> 2, w = m & 3;
        src = ((w == 0) ? Wq : (w == 1) ? Wk : (w == 2) ? Wv : Wo) + (size_t)l * DM * DM;
        dst = (w < 3) ? wt_qkv + (size_t)l * 3 * DM * DM + (size_t)w * DM * DM
                      : wt_o + (size_t)l * DM * DM;
        R = DM; C = DM;
        bx = local & 15; by = local >> 4;
    } else if (tile < 128 + 2048 + 2048) {              // W1 x2: grid (64,16)
        int u = tile - (128 + 2048);
        int l = u >> 10, local = u & 1023;
        src = W1 + (size_t)l * DM * DF; dst = wt_1 + (size_t)l * DF * DM;
        R = DM; C = DF;
        bx = local & 63; by = local >> 6;
    } else {                                            // W2 x2: grid (16,64)
        int u = tile - (128 + 2048 + 2048);
        int l = u >> 10, local = u & 1023;
        src = W2 + (size_t)l * DF * DM; dst = wt_2 + (size_t)l * DM * DF;
        R = DF; C = DM;
        bx = local & 15; by = local >> 4;
    }
    const int c0 = bx * 32, r0 = by * 32;
    const int tx = threadIdx.x, ty = threadIdx.y;
#pragma unroll
    for (int k = 0; k < 32; k += 8)
        t[ty + k][tx] = src[(size_t)(r0 + ty + k) * C + c0 + tx];
    __syncthreads();
#pragma unroll
    for (int k = 0; k < 32; k += 8)
        dst[(size_t)(c0 + ty + k) * R + r0 + tx] = bfbits(t[tx][ty + k]);
}

// ---------------- pos-encoding table + qkv bias concat ----------------
__global__ __launch_bounds__(256) void prep_k(const float* __restrict__ bq,
                                              const float* __restrict__ bk,
                                              const float* __restrict__ bv,
                                              float* __restrict__ bias_qkv,
                                              float* __restrict__ pe) {
    int tid = blockIdx.x * 256 + threadIdx.x;
    if (tid < SEQ * DM) {
        int s = tid >> 9, c = tid & 511;
        int p = c >> 1;
        float div = expf(-(float)(2 * p) * (9.210340371976184f / 512.0f)); // ln(10000)/512
        float ang = (float)s * div;
        pe[tid] = (c & 1) ? cosf(ang) : sinf(ang);
    }
    if (tid < NL * 3 * DM) {
        int l = tid / (3 * DM), r = tid % (3 * DM);
        float v = (r < DM) ? bq[l * DM + r]
                : (r < 2 * DM) ? bk[l * DM + r - DM]
                               : bv[l * DM + r - 2 * DM];
        bias_qkv[tid] = v;
    }
}

// ---------------- cast x (f32) -> bf16 ----------------
__global__ __launch_bounds__(256) void xcast_k(const float* __restrict__ x,
                                               unsigned short* __restrict__ xb, int n) {
    int i = (blockIdx.x * 256 + threadIdx.x) * 4;
    if (i < n) {
        float4 v = *(const float4*)&x[i];
        uint2 o; o.x = pack2(v.x, v.y); o.y = pack2(v.z, v.w);
        *(uint2*)&xb[i] = o;
    }
}

// ---------------- pipelined MFMA GEMM (counted-vmcnt ring, PHASE-SPLIT K-step) ----
// 256-thr (BM=128): 3-slot ring (48 KB -> 3 blk/CU), PD=2, 2 phases. (proven config)
template <int BM, int BN, int MODE>
__global__ __launch_bounds__(256, 2)
void gemm2_k(const unsigned short* __restrict__ A,
             const unsigned short* __restrict__ Wt,
             const float* __restrict__ bias,
             unsigned short* __restrict__ outB,
             const float* __restrict__ pe,
             int Mt, int Nt, int K, int N) {
    constexpr int NTH = 256;
    constexpr int SLOTS = 3;
    constexpr int PD  = 2;
    constexpr int NWC = BN / 64;               // 2
    constexpr int MI  = 4;
    constexpr int JSH = 5;

    __shared__ unsigned short LA[SLOTS][BM * 32];
    __shared__ unsigned short LB[SLOTS][BN * 32];

    const int tid = threadIdx.x, lane = tid & 63, wid = tid >> 6;
    const int wr = wid / NWC, wc = wid % NWC;
    const int lr = lane & 15, grp = lane >> 4;

    int lin = blockIdx.x;
    int base_m = (lin / (8 * Nt)) * 8;
    int Gc = min(8, Mt - base_m);
    int rem = lin - base_m * Nt;
    int mt = base_m + rem % Gc, nt = rem / Gc;
    const int m0 = mt * BM, n0 = nt * BN;

    const int NKT = K >> 5;

    auto stageA = [&](int kt, int part) {
        int slot = kt % SLOTS, k0 = kt << 5;
        int g = part * NTH + tid;
        int row = g >> 2, c = g & 3;
        int src = c ^ ((row >> 1) & 3);
        async16(&LA[slot][g * 8], A + (size_t)(m0 + row) * K + k0 + src * 8);
    };
    auto stageB = [&](int kt, int part) {
        int slot = kt % SLOTS, k0 = kt << 5;
        int g = part * NTH + tid;
        int pos = g >> 2, cs = g & 3;
        int j   = pos >> JSH;
        int wcc = (pos >> 4) & (NWC - 1);
        int lrr = pos & 15;
        int rb  = wcc * 64 + lrr * 4 + j;
        int c   = cs ^ ((rb >> 3) & 3);
        async16(&LB[slot][g * 8], Wt + (size_t)(n0 + rb) * K + k0 + c * 8);
    };

    f32x4 acc[MI][4] = {};

#pragma unroll
    for (int t = 0; t < PD; ++t) {
        stageA(t, 0); stageA(t, 1); stageB(t, 0); stageB(t, 1);
    }

    for (int kt = 0; kt < NKT; ++kt) {
        const int slot = kt % SLOTS;
        const bool pf = (kt + PD < NKT);
        if (kt + 1 < NKT)      asm volatile("s_waitcnt vmcnt(4)" ::: "memory");
        else                   asm volatile("s_waitcnt vmcnt(0)" ::: "memory");
        __builtin_amdgcn_s_barrier();
        __builtin_amdgcn_sched_barrier(0);

        const int bxor = grp ^ ((lr >> 1) & 3);
        bf16x8 af[MI], bf[4];

        // ---- phase 1 ----
#pragma unroll
        for (int i = 0; i < MI; ++i) {
            int ra = wr * (MI * 16) + i * 16 + lr;
            af[i] = *(const bf16x8*)&LA[slot][ra * 32 + ((grp ^ ((ra >> 1) & 3)) << 3)];
        }
#pragma unroll
        for (int j = 0; j < 2; ++j) {
            int pos = j * (16 * NWC) + wc * 16 + lr;
            bf[j] = *(const bf16x8*)&LB[slot][(pos * 4 + bxor) * 8];
        }
        if (pf) { stageA(kt + PD, 0); stageA(kt + PD, 1); }
        __builtin_amdgcn_s_setprio(1);
#pragma unroll
        for (int i = 0; i < MI; ++i)
#pragma unroll
            for (int j = 0; j < 2; ++j)
                acc[i][j] = __builtin_amdgcn_mfma_f32_16x16x32_bf16(af[i], bf[j], acc[i][j], 0, 0, 0);
        __builtin_amdgcn_s_setprio(0);
        __builtin_amdgcn_s_barrier();
        __builtin_amdgcn_sched_barrier(0);

        // ---- phase 2 ----
#pragma unroll
        for (int j = 2; j < 4; ++j) {
            int pos = j * (16 * NWC) + wc * 16 + lr;
            bf[j] = *(const bf16x8*)&LB[slot][(pos * 4 + bxor) * 8];
        }
        if (pf) { stageB(kt + PD, 0); stageB(kt + PD, 1); }
        __builtin_amdgcn_s_setprio(1);
#pragma unroll
        for (int i = 0; i < MI; ++i)
#pragma unroll
            for (int j = 2; j < 4; ++j)
                acc[i][j] = __builtin_amdgcn_mfma_f32_16x16x32_bf16(af[i], bf[j], acc[i][j], 0, 0, 0);
        __builtin_amdgcn_s_setprio(0);
        __builtin_amdgcn_s_barrier();
        __builtin_amdgcn_sched_barrier(0);
    }

    const int colb = n0 + wc * 64 + lr * 4;
    float4 bv4 = *(const float4*)&bias[colb];
#pragma unroll
    for (int i = 0; i < MI; ++i) {
#pragma unroll
        for (int v = 0; v < 4; ++v) {
            int row = m0 + wr * (MI * 16) + i * 16 + grp * 4 + v;
            float f0 = acc[i][0][v] + bv4.x;
            float f1 = acc[i][1][v] + bv4.y;
            float f2 = acc[i][2][v] + bv4.z;
            float f3 = acc[i][3][v] + bv4.w;
            if (MODE == 2) {
                f0 = fmaxf(f0, 0.f); f1 = fmaxf(f1, 0.f);
                f2 = fmaxf(f2, 0.f); f3 = fmaxf(f3, 0.f);
            }
            if (MODE == 3) {
                int s = min(row >> 5, SEQ - 1);
                float4 p4 = *(const float4*)&pe[(size_t)s * DM + colb];
                f0 += p4.x; f1 += p4.y; f2 += p4.z; f3 += p4.w;
            }
            uint2 wv; wv.x = pack2(f0, f1); wv.y = pack2(f2, f3);
            *(uint2*)&outB[(size_t)row * N + colb] = wv;
        }
    }
}

// ---------------- gemm3_k: 256x256 tile, BK=64, 2-slot dbuf, counted-vmcnt phases ----
// (validated round 13 on FFN1) Staging parts needed-order [B0,B1,A0,A2,B2,B3,A1,A3];
// steady-state gates vmcnt(4)/(4)/(4), tail (4)/(2)/(0). WAR: 2-slot, round-13 audit.
template <int MODE>
__global__ __launch_bounds__(512, 2)
void gemm3_k(const unsigned short* __restrict__ A,
             const unsigned short* __restrict__ Wt,
             const float* __restrict__ bias,
             unsigned short* __restrict__ outB,
             int Mt, int Nt, int K, int N) {
    __shared__ unsigned short LA[2][256 * 64];   // 64 KB
    __shared__ unsigned short LB[2][256 * 64];   // 64 KB

    const int tid = threadIdx.x, lane = tid & 63, wid = tid >> 6;
    const int wr = wid >> 2, wc = wid & 3;       // 2 x 4 wave grid
    const int lr = lane & 15, grp = lane >> 4;

    int lin = blockIdx.x;
    int base_m = (lin / (8 * Nt)) * 8;
    int Gc = min(8, Mt - base_m);
    int rem = lin - base_m * Nt;
    int mt = base_m + rem % Gc, nt = rem / Gc;
    const int m0 = mt * 256, n0 = nt * 256;

    const int NKT = K >> 6;

    auto stA = [&](int kt, int part) {
        int slot = kt & 1, k0 = kt << 6;
        int g = part * 512 + tid;
        int row = g >> 3, c = g & 7;
        int src = c ^ (row & 7);
        async16(&LA[slot][g * 8], A + (size_t)(m0 + row) * K + k0 + src * 8);
    };
    auto stB = [&](int kt, int part) {
        int slot = kt & 1, k0 = kt << 6;
        int g = part * 512 + tid;
        int pos = g >> 3, cs = g & 7;
        int j = pos >> 6, wcc = (pos >> 4) & 3, lrr = pos & 15;
        int rb = wcc * 64 + lrr * 4 + j;
        int c = cs ^ (lrr & 7);
        async16(&LB[slot][g * 8], Wt + (size_t)(n0 + rb) * K + k0 + c * 8);
    };

    f32x4 acc[8][4] = {};

    stB(0, 0); stB(0, 1); stA(0, 0); stA(0, 2); stB(0, 2); stB(0, 3); stA(0, 1); stA(0, 3);

    for (int kt = 0; kt < NKT; ++kt) {
        const int slot = kt & 1;
        const bool pf = (kt + 1 < NKT);
        bf16x8 afL[8], afH[8], bf01[4], bf23[4];

        // ---------------- phase 1 ----
        asm volatile("s_waitcnt vmcnt(4)" ::: "memory");
        __builtin_amdgcn_s_barrier();
        __builtin_amdgcn_sched_barrier(0);
#pragma unroll
        for (int j = 0; j < 2; ++j)
#pragma unroll
            for (int kk = 0; kk < 2; ++kk) {
                int pos = j * 64 + wc * 16 + lr;
                bf01[j * 2 + kk] = *(const bf16x8*)&LB[slot][pos * 64 + (((kk * 4 + grp) ^ (lr & 7)) << 3)];
            }
#pragma unroll
        for (int i = 0; i < 4; ++i)
#pragma unroll
            for (int kk = 0; kk < 2; ++kk) {
                int ra = wr * 128 + i * 16 + lr;
                afL[i * 2 + kk] = *(const bf16x8*)&LA[slot][ra * 64 + (((kk * 4 + grp) ^ (ra & 7)) << 3)];
            }
        if (pf) { stB(kt + 1, 0); stB(kt + 1, 1); }
        __builtin_amdgcn_s_setprio(1);
#pragma unroll
        for (int i = 0; i < 4; ++i)
#pragma unroll
            for (int j = 0; j < 2; ++j)
#pragma unroll
                for (int kk = 0; kk < 2; ++kk)
                    acc[i][j] = __builtin_amdgcn_mfma_f32_16x16x32_bf16(afL[i * 2 + kk], bf01[j * 2 + kk], acc[i][j], 0, 0, 0);
        __builtin_amdgcn_s_setprio(0);
        __builtin_amdgcn_sched_barrier(0);

        // ---------------- phase 2 ----
        if (pf) asm volatile("s_waitcnt vmcnt(4)" ::: "memory");
        else    asm volatile("s_waitcnt vmcnt(2)" ::: "memory");
        __builtin_amdgcn_s_barrier();
        __builtin_amdgcn_sched_barrier(0);
#pragma unroll
        for (int j = 0; j < 2; ++j)
#pragma unroll
            for (int kk = 0; kk < 2; ++kk) {
                int pos = (2 + j) * 64 + wc * 16 + lr;
                bf23[j * 2 + kk] = *(const bf16x8*)&LB[slot][pos * 64 + (((kk * 4 + grp) ^ (lr & 7)) << 3)];
            }
        if (pf) { stA(kt + 1, 0); stA(kt + 1, 2); }
        __builtin_amdgcn_s_setprio(1);
#pragma unroll
        for (int i = 0; i < 4; ++i)
#pragma unroll
            for (int j = 0; j < 2; ++j)
#pragma unroll
                for (int kk = 0; kk < 2; ++kk)
                    acc[i][2 + j] = __builtin_amdgcn_mfma_f32_16x16x32_bf16(afL[i * 2 + kk], bf23[j * 2 + kk], acc[i][2 + j], 0, 0, 0);
        __builtin_amdgcn_s_setprio(0);
        __builtin_amdgcn_sched_barrier(0);

        // ---------------- phase 3 ----
        if (pf) asm volatile("s_waitcnt vmcnt(4)" ::: "memory");
        else    asm volatile("s_waitcnt vmcnt(0)" ::: "memory");
        __builtin_amdgcn_s_barrier();
        __builtin_amdgcn_sched_barrier(0);
#pragma unroll
        for (int i = 0; i < 4; ++i)
#pragma unroll
            for (int kk = 0; kk < 2; ++kk) {
                int ra = wr * 128 + (4 + i) * 16 + lr;
                afH[i * 2 + kk] = *(const bf16x8*)&LA[slot][ra * 64 + (((kk * 4 + grp) ^ (ra & 7)) << 3)];
            }
        if (pf) { stB(kt + 1, 2); stB(kt + 1, 3); }
        __builtin_amdgcn_s_setprio(1);
#pragma unroll
        for (int i = 0; i < 4; ++i)
#pragma unroll
            for (int j = 0; j < 2; ++j)
#pragma unroll
                for (int kk = 0; kk < 2; ++kk)
                    acc[4 + i][j] = __builtin_amdgcn_mfma_f32_16x16x32_bf16(afH[i * 2 + kk], bf01[j * 2 + kk], acc[4 + i][j], 0, 0, 0);
        __builtin_amdgcn_s_setprio(0);
        __builtin_amdgcn_sched_barrier(0);

        // ---------------- phase 4 ----
        __builtin_amdgcn_s_barrier();
        __builtin_amdgcn_sched_barrier(0);
        if (pf) { stA(kt + 1, 1); stA(kt + 1, 3); }
        __builtin_amdgcn_s_setprio(1);
#pragma unroll
        for (int i = 0; i < 4; ++i)
#pragma unroll
            for (int j = 0; j < 2; ++j)
#pragma unroll
                for (int kk = 0; kk < 2; ++kk)
                    acc[4 + i][2 + j] = __builtin_amdgcn_mfma_f32_16x16x32_bf16(afH[i * 2 + kk], bf23[j * 2 + kk], acc[4 + i][2 + j], 0, 0, 0);
        __builtin_amdgcn_s_setprio(0);
        __builtin_amdgcn_sched_barrier(0);
    }

    const int colb = n0 + wc * 64 + lr * 4;
    float4 bv4 = *(const float4*)&bias[colb];
#pragma unroll
    for (int i = 0; i < 8; ++i) {
#pragma unroll
        for (int v = 0; v < 4; ++v) {
            int row = m0 + wr * 128 + i * 16 + grp * 4 + v;
            float f0 = acc[i][0][v] + bv4.x;
            float f1 = acc[i][1][v] + bv4.y;
            float f2 = acc[i][2][v] + bv4.z;
            float f3 = acc[i][3][v] + bv4.w;
            if (MODE == 2) {
                f0 = fmaxf(f0, 0.f); f1 = fmaxf(f1, 0.f);
                f2 = fmaxf(f2, 0.f); f3 = fmaxf(f3, 0.f);
            }
            uint2 wv; wv.x = pack2(f0, f1); wv.y = pack2(f2, f3);
            *(uint2*)&outB[(size_t)row * N + colb] = wv;
        }
    }
}

// ---------------- V transpose: qkv V-part -> vT[bh][64][512] (bf16, zero-padded) ----
__global__ __launch_bounds__(256) void vtrans_k(const unsigned short* __restrict__ qkv,
                                                unsigned short* __restrict__ vT) {
    __shared__ unsigned short t[32][72];
    const int s0 = blockIdx.x * 32;
    const int bh = blockIdx.y;
    const int b = bh >> 3, h = bh & 7;
    const int tid = threadIdx.x;
    {
        int sl = tid >> 3;
        int c  = tid & 7;
        int s  = s0 + sl;
        uint4 val = {0, 0, 0, 0};
        if (s < SEQ)
            val = *(const uint4*)&qkv[(size_t)(s * BATCH + b) * (3 * DM) + 2 * DM + h * HD + c * 8];
        *(uint4*)&t[sl][c * 8] = val;
    }
    __syncthreads();
    {
        int d  = tid >> 2;
        int s8 = (tid & 3) * 8;
        unsigned short v[8];
#pragma unroll
        for (int j = 0; j < 8; ++j) v[j] = t[s8 + j][d];
        *(uint4*)&vT[(size_t)(bh * 64 + d) * 512 + s0 + s8] = *(uint4*)v;
    }
}

// ---------------- sliding-window attention, MFMA, QBLK=64, K/V LDS union ----------------
// R16 changes: (1) K rows >= nkeys not staged at all (stale LDS is read by MFMA but
// every consuming score is discarded by the mask select: key > jend >= i for all
// queries in the block; NaN-safe since select discards the value). (2) The full-P
// zero pass is replaced by a 16-col tail zero covering exactly [NT*16, NKS*32)
// (difference is always 0 or 16 cols); written P cols are otherwise exp-masked 0s.
#define QBLK  64
#define NIB   8                  // ceil(500/64)
#define KTIL  11                 // key tiles of 16 -> 176 rows
#define KSTR  72                 // K row stride (shorts)
#define VSTR  200                // V^T row stride (shorts)
#define PSTR  200                // P row stride (shorts)

__global__ __launch_bounds__(256, 3) void attn_k(const unsigned short* __restrict__ qkv,
                                                 const unsigned short* __restrict__ vT,
                                                 unsigned short* __restrict__ ob) {
    __shared__ unsigned short KV[12800];
    __shared__ unsigned short Pl[64 * PSTR];

    const int ib = blockIdx.x & (NIB - 1), bh = blockIdx.x >> 3;
    const int b = bh >> 3, h = bh & 7;
    const int i0 = ib * QBLK;
    const int jbase = max(0, i0 - (WINSZ - 1));
    const int jend  = min(SEQ - 1, i0 + QBLK - 1);
    const int nkeys = jend - jbase + 1;
    const int NT  = (nkeys + 15) >> 4;
    const int NKS = (nkeys + 31) >> 5;
    const int tid = threadIdx.x, lane = tid & 63, w = tid >> 6;
    const int q15 = lane & 15, grp = lane >> 4;

    // ---- stage K rows < nkeys ONLY (rows beyond are mask-discarded) ----
#pragma unroll
    for (int it = 0; it < 6; ++it) {
        int g = it * 256 + tid;
        if (g < nkeys * 8) {
            int row = g >> 3, c = g & 7;
            uint4 val = *(const uint4*)&qkv[(size_t)((jbase + row) * BATCH + b) * (3 * DM)
                                            + DM + h * HD + c * 8];
            *(uint4*)&KV[row * KSTR + c * 8] = val;
        }
    }
    // ---- V -> regs (issue early; written to LDS after QK phase): 64 x 24 chunks ----
    uint4 vreg[6];
#pragma unroll
    for (int it = 0; it < 6; ++it) {
        int g = it * 256 + tid;
        int r = g / 24, c = g - r * 24;
        uint4 val = {0, 0, 0, 0};
        if (c * 8 < nkeys && jbase + c * 8 + 8 <= 512)
            val = *(const uint4*)&vT[(size_t)(bh * 64 + r) * 512 + jbase + c * 8];
        vreg[it] = val;
    }
    // ---- Q -> regs (B-fragments) ----
    bf16x8 qav, qbv;
    {
        int iq = min(i0 + w * 16 + q15, SEQ - 1);
        size_t qrow = (size_t)(iq * BATCH + b) * (3 * DM) + h * HD;
        uint4 a = *(const uint4*)&qkv[qrow + grp * 8];
        uint4 c = *(const uint4*)&qkv[qrow + 32 + grp * 8];
        qav = __builtin_bit_cast(bf16x8, a);
        qbv = __builtin_bit_cast(bf16x8, c);
    }
    __syncthreads();

    // ---- QK^T (S^T layout: row=key, col=query) + mask ----
    const int i = i0 + w * 16 + q15;
    float sc[KTIL][4];
#pragma unroll
    for (int t = 0; t < KTIL; ++t) {
        if (t >= NT) continue;
        f32x4 acc = {};
        int row = t * 16 + q15;
        bf16x8 kf0 = *(const bf16x8*)&KV[row * KSTR + grp * 8];
        acc = __builtin_amdgcn_mfma_f32_16x16x32_bf16(kf0, qav, acc, 0, 0, 0);
        bf16x8 kf1 = *(const bf16x8*)&KV[row * KSTR + 32 + grp * 8];
        acc = __builtin_amdgcn_mfma_f32_16x16x32_bf16(kf1, qbv, acc, 0, 0, 0);
#pragma unroll
        for (int v = 0; v < 4; ++v) {
            int key = jbase + t * 16 + grp * 4 + v;
            bool valid = (key <= i) && (key > i - WINSZ);
            sc[t][v] = valid ? acc[v] * 0.125f : -1e30f;
        }
    }
    // ---- softmax over keys ----
    float m = -1e30f;
#pragma unroll
    for (int t = 0; t < KTIL; ++t) {
        if (t >= NT) continue;
#pragma unroll
        for (int v = 0; v < 4; ++v) m = fmaxf(m, sc[t][v]);
    }
    m = fmaxf(m, __shfl_xor(m, 16));
    m = fmaxf(m, __shfl_xor(m, 32));
    float sum = 0.f;
#pragma unroll
    for (int t = 0; t < KTIL; ++t) {
        if (t >= NT) continue;
#pragma unroll
        for (int v = 0; v < 4; ++v) {
            float p = __expf(sc[t][v] - m);
            sc[t][v] = p;
            sum += p;
        }
    }
    sum += __shfl_xor(sum, 16);
    sum += __shfl_xor(sum, 32);

    __syncthreads();   // all waves done reading K from the union buffer

    // ---- V regs -> LDS (union with K) ----
#pragma unroll
    for (int it = 0; it < 6; ++it) {
        int g = it * 256 + tid;
        int r = g / 24, c = g - r * 24;
        *(uint4*)&KV[r * VSTR + c * 8] = vreg[it];
    }
    // ---- P -> LDS (bf16; row = query, col = key); tail cols [NT*16,NKS*32) zeroed ----
#pragma unroll
    for (int t = 0; t < KTIL; ++t) {
        if (t >= NT) continue;
        uint2 pk;
        pk.x = pack2(sc[t][0], sc[t][1]);
        pk.y = pack2(sc[t][2], sc[t][3]);
        *(uint2*)&Pl[(w * 16 + q15) * PSTR + t * 16 + grp * 4] = pk;
    }
    if (NT * 16 < NKS * 32) {
        uint2 z = {0, 0};
        *(uint2*)&Pl[(w * 16 + q15) * PSTR + NT * 16 + grp * 4] = z;
    }
    __syncthreads();   // Vt ready (P is own-wave)

    // ---- PV: O = P @ V ----
    f32x4 oacc[4] = {};
#pragma unroll
    for (int ks = 0; ks < 6; ++ks) {
        if (ks >= NKS) continue;
        bf16x8 pf = *(const bf16x8*)&Pl[(w * 16 + q15) * PSTR + ks * 32 + grp * 8];
#pragma unroll
        for (int dt = 0; dt < 4; ++dt) {
            bf16x8 vf = *(const bf16x8*)&KV[(dt * 16 + q15) * VSTR + ks * 32 + grp * 8];
            oacc[dt] = __builtin_amdgcn_mfma_f32_16x16x32_bf16(pf, vf, oacc[dt], 0, 0, 0);
        }
    }

    // ---- normalize + store ----
#pragma unroll
    for (int v = 0; v < 4; ++v) {
        float rsv = 1.0f / __shfl(sum, grp * 4 + v);
        int irow = i0 + w * 16 + grp * 4 + v;
        if (irow < SEQ) {
            size_t base = (size_t)(irow * BATCH + b) * DM + h * HD + q15;
#pragma unroll
            for (int dt = 0; dt < 4; ++dt)
                ob[base + dt * 16] = bfbits(oacc[dt][v] * rsv);
        }
    }
}

// ---------------- residual + layernorm (wave per row); bf16 in, bf16 or f32 out ----
template <int FOUT>
__global__ __launch_bounds__(256) void ln_k(const unsigned short* __restrict__ hin,
                                            const unsigned short* __restrict__ yin,
                                            const float* __restrict__ sc,
                                            const float* __restrict__ bi,
                                            unsigned short* __restrict__ hb,
                                            float* __restrict__ fout) {
    int row = blockIdx.x * 4 + (threadIdx.x >> 6);
    int lane = threadIdx.x & 63;
    size_t base = (size_t)row * DM + lane * 8;
    uint4 hw = *(const uint4*)&hin[base];
    uint4 yw = *(const uint4*)&yin[base];
    float x[8] = {blo(hw.x) + blo(yw.x), bhi(hw.x) + bhi(yw.x),
                  blo(hw.y) + blo(yw.y), bhi(hw.y) + bhi(yw.y),
                  blo(hw.z) + blo(yw.z), bhi(hw.z) + bhi(yw.z),
                  blo(hw.w) + blo(yw.w), bhi(hw.w) + bhi(yw.w)};
    float s = 0.f;
#pragma unroll
    for (int k = 0; k < 8; ++k) s += x[k];
#pragma unroll
    for (int off = 32; off; off >>= 1) s += __shfl_xor(s, off);
    float mean = s * (1.f / DM);
    float q = 0.f;
#pragma unroll
    for (int k = 0; k < 8; ++k) { float d = x[k] - mean; q = fmaf(d, d, q); }
#pragma unroll
    for (int off = 32; off; off >>= 1) q += __shfl_xor(q, off);
    float rstd = rsqrtf(q * (1.f / DM) + 1e-5f);
    float4 s0 = *(const float4*)&sc[lane * 8], s1 = *(const float4*)&sc[lane * 8 + 4];
    float4 b0 = *(const float4*)&bi[lane * 8], b1 = *(const float4*)&bi[lane * 8 + 4];
    float o[8];
    o[0] = (x[0] - mean) * rstd * s0.x + b0.x;  o[1] = (x[1] - mean) * rstd * s0.y + b0.y;
    o[2] = (x[2] - mean) * rstd * s0.z + b0.z;  o[3] = (x[3] - mean) * rstd * s0.w + b0.w;
    o[4] = (x[4] - mean) * rstd * s1.x + b1.x;  o[5] = (x[5] - mean) * rstd * s1.y + b1.y;
    o[6] = (x[6] - mean) * rstd * s1.z + b1.z;  o[7] = (x[7] - mean) * rstd * s1.w + b1.w;
    if (FOUT) {
        float4 w0 = {o[0], o[1], o[2], o[3]}, w1 = {o[4], o[5], o[6], o[7]};
        *(float4*)&fout[base] = w0;
        *(float4*)&fout[base + 4] = w1;
    } else {
        uint4 pk = {pack2(o[0], o[1]), pack2(o[2], o[3]), pack2(o[4], o[5]), pack2(o[6], o[7])};
        *(uint4*)&hb[base] = pk;
    }
}

// ---------------- host launch ----------------
extern "C" void kernel_launch(void* const* d_in, const int* in_sizes, int n_in,
                              void* d_out, int out_size, void* d_ws, size_t ws_size,
                              hipStream_t stream) {
    const float* x     = (const float*)d_in[0];
    const float* Wemb  = (const float*)d_in[1];
    const float* bemb  = (const float*)d_in[2];
    const float* Wq    = (const float*)d_in[3];
    const float* bq    = (const float*)d_in[4];
    const float* Wk    = (const float*)d_in[5];
    const float* bk    = (const float*)d_in[6];
    const float* Wv    = (const float*)d_in[7];
    const float* bv    = (const float*)d_in[8];
    const float* Wo    = (const float*)d_in[9];
    const float* bo    = (const float*)d_in[10];
    const float* ln1s  = (const float*)d_in[11];
    const float* ln1b  = (const float*)d_in[12];
    const float* W1    = (const float*)d_in[13];
    const float* b1    = (const float*)d_in[14];
    const float* W2    = (const float*)d_in[15];
    const float* b2    = (const float*)d_in[16];
    const float* ln2s  = (const float*)d_in[17];
    const float* ln2b  = (const float*)d_in[18];

    char* p = (char*)d_ws;
    auto carve = [&](size_t bytes) { char* r = p; p += (bytes + 255) & ~(size_t)255; return r; };

    unsigned short* wt_emb = (unsigned short*)carve((size_t)DM * DIN * 2);
    unsigned short* wt_qkv = (unsigned short*)carve((size_t)NL * 3 * DM * DM * 2);
    unsigned short* wt_o   = (unsigned short*)carve((size_t)NL * DM * DM * 2);
    unsigned short* wt_1   = (unsigned short*)carve((size_t)NL * DF * DM * 2);
    unsigned short* wt_2   = (unsigned short*)carve((size_t)NL * DM * DF * 2);
    float*          biasq  = (float*)carve((size_t)NL * 3 * DM * 4);
    float*          pe     = (float*)carve((size_t)SEQ * DM * 4);
    unsigned short* xb     = (unsigned short*)carve((size_t)MPAD * DIN * 2);
    unsigned short* h      = (unsigned short*)carve((size_t)MPAD * DM * 2);
    unsigned short* ob     = (unsigned short*)carve((size_t)MPAD * DM * 2);
    unsigned short* t0b    = (unsigned short*)carve((size_t)MPAD * DM * 2);
    unsigned short* vT     = (unsigned short*)carve((size_t)BATCH * NH * 64 * 512 * 2 + 1024);
    unsigned short* qkv    = (unsigned short*)carve((size_t)MPAD * DF * 2);
    unsigned short* f1     = qkv;

    dim3 blk256(256);

    // ALL weight transposes in one launch (6272 tiles)
    wprep_k<<<dim3(6272), dim3(32, 8), 0, stream>>>(Wemb, Wq, Wk, Wv, Wo, W1, W2,
                                                    wt_emb, wt_qkv, wt_o, wt_1, wt_2);
    prep_k<<<dim3((SEQ * DM + 255) / 256), blk256, 0, stream>>>(bq, bk, bv, biasq, pe);
    xcast_k<<<dim3(ROWS * DIN / 4 / 256), blk256, 0, stream>>>(x, xb, ROWS * DIN);

    const int Mt256 = MPAD / 256;   // 63
    const int Mt128 = MPAD / 128;   // 126

    // embedding + posenc -> bf16 h (gemm2, MODE 3)
    gemm2_k<128, 128, 3><<<dim3(Mt128 * 4), blk256, 0, stream>>>(
        xb, wt_emb, bemb, h, pe, Mt128, 4, DIN, DM);

    for (int l = 0; l < NL; ++l) {
        // QKV (gemm2, 1512 blocks, 3 blk/CU)
        gemm2_k<128, 128, 1><<<dim3(Mt128 * 12), blk256, 0, stream>>>(
            h, wt_qkv + (size_t)l * 3 * DM * DM, biasq + (size_t)l * 3 * DM,
            qkv, nullptr, Mt128, 12, DM, 3 * DM);
        // V transpose
        vtrans_k<<<dim3(16, BATCH * NH), blk256, 0, stream>>>(qkv, vT);
        // attention
        attn_k<<<dim3(BATCH * NH * NIB), blk256, 0, stream>>>(qkv, vT, ob);
        // O-proj -> t0b (gemm2)
        gemm2_k<128, 128, 1><<<dim3(Mt128 * 4), blk256, 0, stream>>>(
            ob, wt_o + (size_t)l * DM * DM, bo + (size_t)l * DM,
            t0b, nullptr, Mt128, 4, DM, DM);
        // LN1
        ln_k<0><<<dim3(ROWS / 4), blk256, 0, stream>>>(h, t0b, ln1s + (size_t)l * DM, ln1b + (size_t)l * DM, h, nullptr);
        // FFN1 -> f1 (relu): gemm3 (validated)
        gemm3_k<2><<<dim3(Mt256 * 8), dim3(512), 0, stream>>>(
            h, wt_1 + (size_t)l * DF * DM, b1 + (size_t)l * DF,
            f1, Mt256, 8, DM, DF);
        // FFN2 -> t0b (gemm2)
        gemm2_k<128, 128, 1><<<dim3(Mt128 * 4), blk256, 0, stream>>>(
            f1, wt_2 + (size_t)l * DM * DF, b2 + (size_t)l * DM,
            t0b, nullptr, Mt128, 4, DF, DM);
        // LN2
        if (l == NL - 1)
            ln_k<1><<<dim3(ROWS / 4), blk256, 0, stream>>>(h, t0b, ln2s + (size_t)l * DM, ln2b + (size_t)l * DM, nullptr, (float*)d_out);
        else
            ln_k<0><<<dim3(ROWS / 4), blk256, 0, stream>>>(h, t0b, ln2s + (size_t)l * DM, ln2b + (size_t)l * DM, h, nullptr);
    }
}

// Round 17
// 386.522 us; speedup vs baseline: 1.1117x; 1.0162x over previous
//
#include <hip/hip_runtime.h>
#include <stdint.h>

// ---------------- problem constants ----------------
#define SEQ   500
#define BATCH 32
#define DIN   256
#define DM    512
#define NH    8
#define NL    2
#define DF    2048
#define WINSZ 100
#define HD    64          // DM/NH
#define ROWS  (SEQ*BATCH) // 16000
#define MPAD  16128       // 63*256 = 126*128

typedef __bf16 bf16x8 __attribute__((ext_vector_type(8)));
typedef float  f32x4  __attribute__((ext_vector_type(4)));

// ---------------- helpers ----------------
__device__ __forceinline__ unsigned short bfbits(float f) {
    unsigned int u = __builtin_bit_cast(unsigned int, f);
    u = u + 0x7fffu + ((u >> 16) & 1u);           // RNE
    return (unsigned short)(u >> 16);
}
__device__ __forceinline__ unsigned int pack2(float a, float b) {
    return (unsigned int)bfbits(a) | ((unsigned int)bfbits(b) << 16);
}
__device__ __forceinline__ float blo(unsigned int u) { return __builtin_bit_cast(float, u << 16); }
__device__ __forceinline__ float bhi(unsigned int u) { return __builtin_bit_cast(float, u & 0xffff0000u); }

__device__ __forceinline__ void async16(void* lds, const void* g) {
    __builtin_amdgcn_global_load_lds((__attribute__((address_space(1))) void*)(void*)g,
                                     (__attribute__((address_space(3))) void*)(void*)lds,
                                     16, 0, 0);
}

// ---------------- merged weight prep: all 13 transposes in ONE launch ----------------
__global__ __launch_bounds__(256) void wprep_k(const float* __restrict__ Wemb,
                                               const float* __restrict__ Wq,
                                               const float* __restrict__ Wk,
                                               const float* __restrict__ Wv,
                                               const float* __restrict__ Wo,
                                               const float* __restrict__ W1,
                                               const float* __restrict__ W2,
                                               unsigned short* __restrict__ wt_emb,
                                               unsigned short* __restrict__ wt_qkv,
                                               unsigned short* __restrict__ wt_o,
                                               unsigned short* __restrict__ wt_1,
                                               unsigned short* __restrict__ wt_2) {
    __shared__ float t[32][33];
    const int tile = blockIdx.x;
    const float* src;
    unsigned short* dst;
    int R, C, bx, by;
    if (tile < 128) {                                   // Wemb: grid (16,8)
        src = Wemb; dst = wt_emb; R = DIN; C = DM;
        bx = tile & 15; by = tile >> 4;
    } else if (tile < 128 + 2048) {                     // 512x512 x8: grid (16,16) each
        int u = tile - 128;
        int m = u >> 8, local = u & 255;
        int l = m >> 2, w = m & 3;
        src = ((w == 0) ? Wq : (w == 1) ? Wk : (w == 2) ? Wv : Wo) + (size_t)l * DM * DM;
        dst = (w < 3) ? wt_qkv + (size_t)l * 3 * DM * DM + (size_t)w * DM * DM
                      : wt_o + (size_t)l * DM * DM;
        R = DM; C = DM;
        bx = local & 15; by = local >> 4;
    } else if (tile < 128 + 2048 + 2048) {              // W1 x2: grid (64,16)
        int u = tile - (128 + 2048);
        int l = u >> 10, local = u & 1023;
        src = W1 + (size_t)l * DM * DF; dst = wt_1 + (size_t)l * DF * DM;
        R = DM; C = DF;
        bx = local & 63; by = local >> 6;
    } else {                                            // W2 x2: grid (16,64)
        int u = tile - (128 + 2048 + 2048);
        int l = u >> 10, local = u & 1023;
        src = W2 + (size_t)l * DF * DM; dst = wt_2 + (size_t)l * DM * DF;
        R = DF; C = DM;
        bx = local & 15; by = local >> 4;
    }
    const int c0 = bx * 32, r0 = by * 32;
    const int tx = threadIdx.x, ty = threadIdx.y;
#pragma unroll
    for (int k = 0; k < 32; k += 8)
        t[ty + k][tx] = src[(size_t)(r0 + ty + k) * C + c0 + tx];
    __syncthreads();
#pragma unroll
    for (int k = 0; k < 32; k += 8)
        dst[(size_t)(c0 + ty + k) * R + r0 + tx] = bfbits(t[tx][ty + k]);
}

// ---------------- pos-encoding table + qkv bias concat ----------------
__global__ __launch_bounds__(256) void prep_k(const float* __restrict__ bq,
                                              const float* __restrict__ bk,
                                              const float* __restrict__ bv,
                                              float* __restrict__ bias_qkv,
                                              float* __restrict__ pe) {
    int tid = blockIdx.x * 256 + threadIdx.x;
    if (tid < SEQ * DM) {
        int s = tid >> 9, c = tid & 511;
        int p = c >> 1;
        float div = expf(-(float)(2 * p) * (9.210340371976184f / 512.0f)); // ln(10000)/512
        float ang = (float)s * div;
        pe[tid] = (c & 1) ? cosf(ang) : sinf(ang);
    }
    if (tid < NL * 3 * DM) {
        int l = tid / (3 * DM), r = tid % (3 * DM);
        float v = (r < DM) ? bq[l * DM + r]
                : (r < 2 * DM) ? bk[l * DM + r - DM]
                               : bv[l * DM + r - 2 * DM];
        bias_qkv[tid] = v;
    }
}

// ---------------- cast x (f32) -> bf16 ----------------
__global__ __launch_bounds__(256) void xcast_k(const float* __restrict__ x,
                                               unsigned short* __restrict__ xb, int n) {
    int i = (blockIdx.x * 256 + threadIdx.x) * 4;
    if (i < n) {
        float4 v = *(const float4*)&x[i];
        uint2 o; o.x = pack2(v.x, v.y); o.y = pack2(v.z, v.w);
        *(uint2*)&xb[i] = o;
    }
}

// ---------------- pipelined MFMA GEMM (counted-vmcnt ring, PHASE-SPLIT K-step) ----
// 256-thr (BM=128): 3-slot ring (48 KB -> 3 blk/CU), PD=2, 2 phases. (proven config)
template <int BM, int BN, int MODE>
__global__ __launch_bounds__(256, 2)
void gemm2_k(const unsigned short* __restrict__ A,
             const unsigned short* __restrict__ Wt,
             const float* __restrict__ bias,
             unsigned short* __restrict__ outB,
             const float* __restrict__ pe,
             int Mt, int Nt, int K, int N) {
    constexpr int NTH = 256;
    constexpr int SLOTS = 3;
    constexpr int PD  = 2;
    constexpr int NWC = BN / 64;               // 2
    constexpr int MI  = 4;
    constexpr int JSH = 5;

    __shared__ unsigned short LA[SLOTS][BM * 32];
    __shared__ unsigned short LB[SLOTS][BN * 32];

    const int tid = threadIdx.x, lane = tid & 63, wid = tid >> 6;
    const int wr = wid / NWC, wc = wid % NWC;
    const int lr = lane & 15, grp = lane >> 4;

    int lin = blockIdx.x;
    int base_m = (lin / (8 * Nt)) * 8;
    int Gc = min(8, Mt - base_m);
    int rem = lin - base_m * Nt;
    int mt = base_m + rem % Gc, nt = rem / Gc;
    const int m0 = mt * BM, n0 = nt * BN;

    const int NKT = K >> 5;

    auto stageA = [&](int kt, int part) {
        int slot = kt % SLOTS, k0 = kt << 5;
        int g = part * NTH + tid;
        int row = g >> 2, c = g & 3;
        int src = c ^ ((row >> 1) & 3);
        async16(&LA[slot][g * 8], A + (size_t)(m0 + row) * K + k0 + src * 8);
    };
    auto stageB = [&](int kt, int part) {
        int slot = kt % SLOTS, k0 = kt << 5;
        int g = part * NTH + tid;
        int pos = g >> 2, cs = g & 3;
        int j   = pos >> JSH;
        int wcc = (pos >> 4) & (NWC - 1);
        int lrr = pos & 15;
        int rb  = wcc * 64 + lrr * 4 + j;
        int c   = cs ^ ((rb >> 3) & 3);
        async16(&LB[slot][g * 8], Wt + (size_t)(n0 + rb) * K + k0 + c * 8);
    };

    f32x4 acc[MI][4] = {};

#pragma unroll
    for (int t = 0; t < PD; ++t) {
        stageA(t, 0); stageA(t, 1); stageB(t, 0); stageB(t, 1);
    }

    for (int kt = 0; kt < NKT; ++kt) {
        const int slot = kt % SLOTS;
        const bool pf = (kt + PD < NKT);
        if (kt + 1 < NKT)      asm volatile("s_waitcnt vmcnt(4)" ::: "memory");
        else                   asm volatile("s_waitcnt vmcnt(0)" ::: "memory");
        __builtin_amdgcn_s_barrier();
        __builtin_amdgcn_sched_barrier(0);

        const int bxor = grp ^ ((lr >> 1) & 3);
        bf16x8 af[MI], bf[4];

        // ---- phase 1 ----
#pragma unroll
        for (int i = 0; i < MI; ++i) {
            int ra = wr * (MI * 16) + i * 16 + lr;
            af[i] = *(const bf16x8*)&LA[slot][ra * 32 + ((grp ^ ((ra >> 1) & 3)) << 3)];
        }
#pragma unroll
        for (int j = 0; j < 2; ++j) {
            int pos = j * (16 * NWC) + wc * 16 + lr;
            bf[j] = *(const bf16x8*)&LB[slot][(pos * 4 + bxor) * 8];
        }
        if (pf) { stageA(kt + PD, 0); stageA(kt + PD, 1); }
        __builtin_amdgcn_s_setprio(1);
#pragma unroll
        for (int i = 0; i < MI; ++i)
#pragma unroll
            for (int j = 0; j < 2; ++j)
                acc[i][j] = __builtin_amdgcn_mfma_f32_16x16x32_bf16(af[i], bf[j], acc[i][j], 0, 0, 0);
        __builtin_amdgcn_s_setprio(0);
        __builtin_amdgcn_s_barrier();
        __builtin_amdgcn_sched_barrier(0);

        // ---- phase 2 ----
#pragma unroll
        for (int j = 2; j < 4; ++j) {
            int pos = j * (16 * NWC) + wc * 16 + lr;
            bf[j] = *(const bf16x8*)&LB[slot][(pos * 4 + bxor) * 8];
        }
        if (pf) { stageB(kt + PD, 0); stageB(kt + PD, 1); }
        __builtin_amdgcn_s_setprio(1);
#pragma unroll
        for (int i = 0; i < MI; ++i)
#pragma unroll
            for (int j = 2; j < 4; ++j)
                acc[i][j] = __builtin_amdgcn_mfma_f32_16x16x32_bf16(af[i], bf[j], acc[i][j], 0, 0, 0);
        __builtin_amdgcn_s_setprio(0);
        __builtin_amdgcn_s_barrier();
        __builtin_amdgcn_sched_barrier(0);
    }

    const int colb = n0 + wc * 64 + lr * 4;
    float4 bv4 = *(const float4*)&bias[colb];
#pragma unroll
    for (int i = 0; i < MI; ++i) {
#pragma unroll
        for (int v = 0; v < 4; ++v) {
            int row = m0 + wr * (MI * 16) + i * 16 + grp * 4 + v;
            float f0 = acc[i][0][v] + bv4.x;
            float f1 = acc[i][1][v] + bv4.y;
            float f2 = acc[i][2][v] + bv4.z;
            float f3 = acc[i][3][v] + bv4.w;
            if (MODE == 2) {
                f0 = fmaxf(f0, 0.f); f1 = fmaxf(f1, 0.f);
                f2 = fmaxf(f2, 0.f); f3 = fmaxf(f3, 0.f);
            }
            if (MODE == 3) {
                int s = min(row >> 5, SEQ - 1);
                float4 p4 = *(const float4*)&pe[(size_t)s * DM + colb];
                f0 += p4.x; f1 += p4.y; f2 += p4.z; f3 += p4.w;
            }
            uint2 wv; wv.x = pack2(f0, f1); wv.y = pack2(f2, f3);
            *(uint2*)&outB[(size_t)row * N + colb] = wv;
        }
    }
}

// ---------------- gemm3_k: 256x256 tile, BK=64, 2-slot dbuf, counted-vmcnt phases ----
// (validated round 13 on FFN1) Staging parts needed-order [B0,B1,A0,A2,B2,B3,A1,A3];
// steady-state gates vmcnt(4)/(4)/(4), tail (4)/(2)/(0). WAR: 2-slot, round-13 audit
// (holds for any NKT>=1).
// R17: split-K support. Grid = Mt*Nt*SK; kh = blockIdx.x / (Mt*Nt) selects K-half:
// A/Wt column window [kh*Ksub, kh*Ksub+Ksub) with row stride Kfull; output goes to
// out0 (kh=0) or out1 (kh=1); partial sums are combined (plus bias vector) in ln_k.
// MODE 0: raw (no bias)   MODE 2: relu(+bias)
template <int MODE>
__global__ __launch_bounds__(512, 2)
void gemm3_k(const unsigned short* __restrict__ A,
             const unsigned short* __restrict__ Wt,
             const float* __restrict__ bias,
             unsigned short* __restrict__ out0,
             unsigned short* __restrict__ out1,
             int Mt, int Nt, int Ksub, int Kfull, int N) {
    __shared__ unsigned short LA[2][256 * 64];   // 64 KB
    __shared__ unsigned short LB[2][256 * 64];   // 64 KB

    const int tid = threadIdx.x, lane = tid & 63, wid = tid >> 6;
    const int wr = wid >> 2, wc = wid & 3;       // 2 x 4 wave grid
    const int lr = lane & 15, grp = lane >> 4;

    const int mn = Mt * Nt;
    const int kh = blockIdx.x / mn;
    int lin = blockIdx.x % mn;
    int base_m = (lin / (8 * Nt)) * 8;
    int Gc = min(8, Mt - base_m);
    int rem = lin - base_m * Nt;
    int mt = base_m + rem % Gc, nt = rem / Gc;
    const int m0 = mt * 256, n0 = nt * 256;
    const int kbase = kh * Ksub;
    unsigned short* outp = kh ? out1 : out0;

    const int NKT = Ksub >> 6;

    auto stA = [&](int kt, int part) {
        int slot = kt & 1, k0 = kbase + (kt << 6);
        int g = part * 512 + tid;
        int row = g >> 3, c = g & 7;
        int src = c ^ (row & 7);
        async16(&LA[slot][g * 8], A + (size_t)(m0 + row) * Kfull + k0 + src * 8);
    };
    auto stB = [&](int kt, int part) {
        int slot = kt & 1, k0 = kbase + (kt << 6);
        int g = part * 512 + tid;
        int pos = g >> 3, cs = g & 7;
        int j = pos >> 6, wcc = (pos >> 4) & 3, lrr = pos & 15;
        int rb = wcc * 64 + lrr * 4 + j;
        int c = cs ^ (lrr & 7);
        async16(&LB[slot][g * 8], Wt + (size_t)(n0 + rb) * Kfull + k0 + c * 8);
    };

    f32x4 acc[8][4] = {};

    stB(0, 0); stB(0, 1); stA(0, 0); stA(0, 2); stB(0, 2); stB(0, 3); stA(0, 1); stA(0, 3);

    for (int kt = 0; kt < NKT; ++kt) {
        const int slot = kt & 1;
        const bool pf = (kt + 1 < NKT);
        bf16x8 afL[8], afH[8], bf01[4], bf23[4];

        // ---------------- phase 1 ----
        asm volatile("s_waitcnt vmcnt(4)" ::: "memory");
        __builtin_amdgcn_s_barrier();
        __builtin_amdgcn_sched_barrier(0);
#pragma unroll
        for (int j = 0; j < 2; ++j)
#pragma unroll
            for (int kk = 0; kk < 2; ++kk) {
                int pos = j * 64 + wc * 16 + lr;
                bf01[j * 2 + kk] = *(const bf16x8*)&LB[slot][pos * 64 + (((kk * 4 + grp) ^ (lr & 7)) << 3)];
            }
#pragma unroll
        for (int i = 0; i < 4; ++i)
#pragma unroll
            for (int kk = 0; kk < 2; ++kk) {
                int ra = wr * 128 + i * 16 + lr;
                afL[i * 2 + kk] = *(const bf16x8*)&LA[slot][ra * 64 + (((kk * 4 + grp) ^ (ra & 7)) << 3)];
            }
        if (pf) { stB(kt + 1, 0); stB(kt + 1, 1); }
        __builtin_amdgcn_s_setprio(1);
#pragma unroll
        for (int i = 0; i < 4; ++i)
#pragma unroll
            for (int j = 0; j < 2; ++j)
#pragma unroll
                for (int kk = 0; kk < 2; ++kk)
                    acc[i][j] = __builtin_amdgcn_mfma_f32_16x16x32_bf16(afL[i * 2 + kk], bf01[j * 2 + kk], acc[i][j], 0, 0, 0);
        __builtin_amdgcn_s_setprio(0);
        __builtin_amdgcn_sched_barrier(0);

        // ---------------- phase 2 ----
        if (pf) asm volatile("s_waitcnt vmcnt(4)" ::: "memory");
        else    asm volatile("s_waitcnt vmcnt(2)" ::: "memory");
        __builtin_amdgcn_s_barrier();
        __builtin_amdgcn_sched_barrier(0);
#pragma unroll
        for (int j = 0; j < 2; ++j)
#pragma unroll
            for (int kk = 0; kk < 2; ++kk) {
                int pos = (2 + j) * 64 + wc * 16 + lr;
                bf23[j * 2 + kk] = *(const bf16x8*)&LB[slot][pos * 64 + (((kk * 4 + grp) ^ (lr & 7)) << 3)];
            }
        if (pf) { stA(kt + 1, 0); stA(kt + 1, 2); }
        __builtin_amdgcn_s_setprio(1);
#pragma unroll
        for (int i = 0; i < 4; ++i)
#pragma unroll
            for (int j = 0; j < 2; ++j)
#pragma unroll
                for (int kk = 0; kk < 2; ++kk)
                    acc[i][2 + j] = __builtin_amdgcn_mfma_f32_16x16x32_bf16(afL[i * 2 + kk], bf23[j * 2 + kk], acc[i][2 + j], 0, 0, 0);
        __builtin_amdgcn_s_setprio(0);
        __builtin_amdgcn_sched_barrier(0);

        // ---------------- phase 3 ----
        if (pf) asm volatile("s_waitcnt vmcnt(4)" ::: "memory");
        else    asm volatile("s_waitcnt vmcnt(0)" ::: "memory");
        __builtin_amdgcn_s_barrier();
        __builtin_amdgcn_sched_barrier(0);
#pragma unroll
        for (int i = 0; i < 4; ++i)
#pragma unroll
            for (int kk = 0; kk < 2; ++kk) {
                int ra = wr * 128 + (4 + i) * 16 + lr;
                afH[i * 2 + kk] = *(const bf16x8*)&LA[slot][ra * 64 + (((kk * 4 + grp) ^ (ra & 7)) << 3)];
            }
        if (pf) { stB(kt + 1, 2); stB(kt + 1, 3); }
        __builtin_amdgcn_s_setprio(1);
#pragma unroll
        for (int i = 0; i < 4; ++i)
#pragma unroll
            for (int j = 0; j < 2; ++j)
#pragma unroll
                for (int kk = 0; kk < 2; ++kk)
                    acc[4 + i][j] = __builtin_amdgcn_mfma_f32_16x16x32_bf16(afH[i * 2 + kk], bf01[j * 2 + kk], acc[4 + i][j], 0, 0, 0);
        __builtin_amdgcn_s_setprio(0);
        __builtin_amdgcn_sched_barrier(0);

        // ---------------- phase 4 ----
        __builtin_amdgcn_s_barrier();
        __builtin_amdgcn_sched_barrier(0);
        if (pf) { stA(kt + 1, 1); stA(kt + 1, 3); }
        __builtin_amdgcn_s_setprio(1);
#pragma unroll
        for (int i = 0; i < 4; ++i)
#pragma unroll
            for (int j = 0; j < 2; ++j)
#pragma unroll
                for (int kk = 0; kk < 2; ++kk)
                    acc[4 + i][2 + j] = __builtin_amdgcn_mfma_f32_16x16x32_bf16(afH[i * 2 + kk], bf23[j * 2 + kk], acc[4 + i][2 + j], 0, 0, 0);
        __builtin_amdgcn_s_setprio(0);
        __builtin_amdgcn_sched_barrier(0);
    }

    const int colb = n0 + wc * 64 + lr * 4;
    float4 bv4 = {0.f, 0.f, 0.f, 0.f};
    if constexpr (MODE != 0) bv4 = *(const float4*)&bias[colb];
#pragma unroll
    for (int i = 0; i < 8; ++i) {
#pragma unroll
        for (int v = 0; v < 4; ++v) {
            int row = m0 + wr * 128 + i * 16 + grp * 4 + v;
            float f0 = acc[i][0][v] + bv4.x;
            float f1 = acc[i][1][v] + bv4.y;
            float f2 = acc[i][2][v] + bv4.z;
            float f3 = acc[i][3][v] + bv4.w;
            if (MODE == 2) {
                f0 = fmaxf(f0, 0.f); f1 = fmaxf(f1, 0.f);
                f2 = fmaxf(f2, 0.f); f3 = fmaxf(f3, 0.f);
            }
            uint2 wv; wv.x = pack2(f0, f1); wv.y = pack2(f2, f3);
            *(uint2*)&outp[(size_t)row * N + colb] = wv;
        }
    }
}

// ---------------- V transpose: qkv V-part -> vT[bh][64][512] (bf16, zero-padded) ----
__global__ __launch_bounds__(256) void vtrans_k(const unsigned short* __restrict__ qkv,
                                                unsigned short* __restrict__ vT) {
    __shared__ unsigned short t[32][72];
    const int s0 = blockIdx.x * 32;
    const int bh = blockIdx.y;
    const int b = bh >> 3, h = bh & 7;
    const int tid = threadIdx.x;
    {
        int sl = tid >> 3;
        int c  = tid & 7;
        int s  = s0 + sl;
        uint4 val = {0, 0, 0, 0};
        if (s < SEQ)
            val = *(const uint4*)&qkv[(size_t)(s * BATCH + b) * (3 * DM) + 2 * DM + h * HD + c * 8];
        *(uint4*)&t[sl][c * 8] = val;
    }
    __syncthreads();
    {
        int d  = tid >> 2;
        int s8 = (tid & 3) * 8;
        unsigned short v[8];
#pragma unroll
        for (int j = 0; j < 8; ++j) v[j] = t[s8 + j][d];
        *(uint4*)&vT[(size_t)(bh * 64 + d) * 512 + s0 + s8] = *(uint4*)v;
    }
}

// ---------------- sliding-window attention, MFMA, QBLK=64, K/V LDS union ----------------
#define QBLK  64
#define NIB   8                  // ceil(500/64)
#define KTIL  11                 // key tiles of 16 -> 176 rows
#define KSTR  72                 // K row stride (shorts)
#define VSTR  200                // V^T row stride (shorts)
#define PSTR  200                // P row stride (shorts)

__global__ __launch_bounds__(256, 3) void attn_k(const unsigned short* __restrict__ qkv,
                                                 const unsigned short* __restrict__ vT,
                                                 unsigned short* __restrict__ ob) {
    __shared__ unsigned short KV[12800];
    __shared__ unsigned short Pl[64 * PSTR];

    const int ib = blockIdx.x & (NIB - 1), bh = blockIdx.x >> 3;
    const int b = bh >> 3, h = bh & 7;
    const int i0 = ib * QBLK;
    const int jbase = max(0, i0 - (WINSZ - 1));
    const int jend  = min(SEQ - 1, i0 + QBLK - 1);
    const int nkeys = jend - jbase + 1;
    const int NT  = (nkeys + 15) >> 4;
    const int NKS = (nkeys + 31) >> 5;
    const int tid = threadIdx.x, lane = tid & 63, w = tid >> 6;
    const int q15 = lane & 15, grp = lane >> 4;

    // ---- stage K rows < nkeys ONLY (rows beyond are mask-discarded) ----
#pragma unroll
    for (int it = 0; it < 6; ++it) {
        int g = it * 256 + tid;
        if (g < nkeys * 8) {
            int row = g >> 3, c = g & 7;
            uint4 val = *(const uint4*)&qkv[(size_t)((jbase + row) * BATCH + b) * (3 * DM)
                                            + DM + h * HD + c * 8];
            *(uint4*)&KV[row * KSTR + c * 8] = val;
        }
    }
    // ---- V -> regs (issue early; written to LDS after QK phase): 64 x 24 chunks ----
    uint4 vreg[6];
#pragma unroll
    for (int it = 0; it < 6; ++it) {
        int g = it * 256 + tid;
        int r = g / 24, c = g - r * 24;
        uint4 val = {0, 0, 0, 0};
        if (c * 8 < nkeys && jbase + c * 8 + 8 <= 512)
            val = *(const uint4*)&vT[(size_t)(bh * 64 + r) * 512 + jbase + c * 8];
        vreg[it] = val;
    }
    // ---- Q -> regs (B-fragments) ----
    bf16x8 qav, qbv;
    {
        int iq = min(i0 + w * 16 + q15, SEQ - 1);
        size_t qrow = (size_t)(iq * BATCH + b) * (3 * DM) + h * HD;
        uint4 a = *(const uint4*)&qkv[qrow + grp * 8];
        uint4 c = *(const uint4*)&qkv[qrow + 32 + grp * 8];
        qav = __builtin_bit_cast(bf16x8, a);
        qbv = __builtin_bit_cast(bf16x8, c);
    }
    __syncthreads();

    // ---- QK^T (S^T layout: row=key, col=query) + mask ----
    const int i = i0 + w * 16 + q15;
    float sc[KTIL][4];
#pragma unroll
    for (int t = 0; t < KTIL; ++t) {
        if (t >= NT) continue;
        f32x4 acc = {};
        int row = t * 16 + q15;
        bf16x8 kf0 = *(const bf16x8*)&KV[row * KSTR + grp * 8];
        acc = __builtin_amdgcn_mfma_f32_16x16x32_bf16(kf0, qav, acc, 0, 0, 0);
        bf16x8 kf1 = *(const bf16x8*)&KV[row * KSTR + 32 + grp * 8];
        acc = __builtin_amdgcn_mfma_f32_16x16x32_bf16(kf1, qbv, acc, 0, 0, 0);
#pragma unroll
        for (int v = 0; v < 4; ++v) {
            int key = jbase + t * 16 + grp * 4 + v;
            bool valid = (key <= i) && (key > i - WINSZ);
            sc[t][v] = valid ? acc[v] * 0.125f : -1e30f;
        }
    }
    // ---- softmax over keys ----
    float m = -1e30f;
#pragma unroll
    for (int t = 0; t < KTIL; ++t) {
        if (t >= NT) continue;
#pragma unroll
        for (int v = 0; v < 4; ++v) m = fmaxf(m, sc[t][v]);
    }
    m = fmaxf(m, __shfl_xor(m, 16));
    m = fmaxf(m, __shfl_xor(m, 32));
    float sum = 0.f;
#pragma unroll
    for (int t = 0; t < KTIL; ++t) {
        if (t >= NT) continue;
#pragma unroll
        for (int v = 0; v < 4; ++v) {
            float p = __expf(sc[t][v] - m);
            sc[t][v] = p;
            sum += p;
        }
    }
    sum += __shfl_xor(sum, 16);
    sum += __shfl_xor(sum, 32);

    __syncthreads();   // all waves done reading K from the union buffer

    // ---- V regs -> LDS (union with K) ----
#pragma unroll
    for (int it = 0; it < 6; ++it) {
        int g = it * 256 + tid;
        int r = g / 24, c = g - r * 24;
        *(uint4*)&KV[r * VSTR + c * 8] = vreg[it];
    }
    // ---- P -> LDS (bf16); tail cols [NT*16,NKS*32) zeroed ----
#pragma unroll
    for (int t = 0; t < KTIL; ++t) {
        if (t >= NT) continue;
        uint2 pk;
        pk.x = pack2(sc[t][0], sc[t][1]);
        pk.y = pack2(sc[t][2], sc[t][3]);
        *(uint2*)&Pl[(w * 16 + q15) * PSTR + t * 16 + grp * 4] = pk;
    }
    if (NT * 16 < NKS * 32) {
        uint2 z = {0, 0};
        *(uint2*)&Pl[(w * 16 + q15) * PSTR + NT * 16 + grp * 4] = z;
    }
    __syncthreads();   // Vt ready (P is own-wave)

    // ---- PV: O = P @ V ----
    f32x4 oacc[4] = {};
#pragma unroll
    for (int ks = 0; ks < 6; ++ks) {
        if (ks >= NKS) continue;
        bf16x8 pf = *(const bf16x8*)&Pl[(w * 16 + q15) * PSTR + ks * 32 + grp * 8];
#pragma unroll
        for (int dt = 0; dt < 4; ++dt) {
            bf16x8 vf = *(const bf16x8*)&KV[(dt * 16 + q15) * VSTR + ks * 32 + grp * 8];
            oacc[dt] = __builtin_amdgcn_mfma_f32_16x16x32_bf16(pf, vf, oacc[dt], 0, 0, 0);
        }
    }

    // ---- normalize + store ----
#pragma unroll
    for (int v = 0; v < 4; ++v) {
        float rsv = 1.0f / __shfl(sum, grp * 4 + v);
        int irow = i0 + w * 16 + grp * 4 + v;
        if (irow < SEQ) {
            size_t base = (size_t)(irow * BATCH + b) * DM + h * HD + q15;
#pragma unroll
            for (int dt = 0; dt < 4; ++dt)
                ob[base + dt * 16] = bfbits(oacc[dt][v] * rsv);
        }
    }
}

// ---------------- residual + layernorm; bf16 in, sums TWO partials + bias vector ----
// x = h + y0 + y1 + bvec[col]; FOUT=0 -> bf16 h (in-place safe), FOUT=1 -> f32 d_out.
template <int FOUT>
__global__ __launch_bounds__(256) void ln_k(const unsigned short* __restrict__ hin,
                                            const unsigned short* __restrict__ y0,
                                            const unsigned short* __restrict__ y1,
                                            const float* __restrict__ bvec,
                                            const float* __restrict__ sc,
                                            const float* __restrict__ bi,
                                            unsigned short* __restrict__ hb,
                                            float* __restrict__ fout) {
    int row = blockIdx.x * 4 + (threadIdx.x >> 6);
    int lane = threadIdx.x & 63;
    size_t base = (size_t)row * DM + lane * 8;
    uint4 hw = *(const uint4*)&hin[base];
    uint4 ya = *(const uint4*)&y0[base];
    uint4 yb = *(const uint4*)&y1[base];
    float4 bv0 = *(const float4*)&bvec[lane * 8], bv1 = *(const float4*)&bvec[lane * 8 + 4];
    float x[8] = {blo(hw.x) + blo(ya.x) + blo(yb.x) + bv0.x,
                  bhi(hw.x) + bhi(ya.x) + bhi(yb.x) + bv0.y,
                  blo(hw.y) + blo(ya.y) + blo(yb.y) + bv0.z,
                  bhi(hw.y) + bhi(ya.y) + bhi(yb.y) + bv0.w,
                  blo(hw.z) + blo(ya.z) + blo(yb.z) + bv1.x,
                  bhi(hw.z) + bhi(ya.z) + bhi(yb.z) + bv1.y,
                  blo(hw.w) + blo(ya.w) + blo(yb.w) + bv1.z,
                  bhi(hw.w) + bhi(ya.w) + bhi(yb.w) + bv1.w};
    float s = 0.f;
#pragma unroll
    for (int k = 0; k < 8; ++k) s += x[k];
#pragma unroll
    for (int off = 32; off; off >>= 1) s += __shfl_xor(s, off);
    float mean = s * (1.f / DM);
    float q = 0.f;
#pragma unroll
    for (int k = 0; k < 8; ++k) { float d = x[k] - mean; q = fmaf(d, d, q); }
#pragma unroll
    for (int off = 32; off; off >>= 1) q += __shfl_xor(q, off);
    float rstd = rsqrtf(q * (1.f / DM) + 1e-5f);
    float4 s0 = *(const float4*)&sc[lane * 8], s1 = *(const float4*)&sc[lane * 8 + 4];
    float4 b0 = *(const float4*)&bi[lane * 8], b1 = *(const float4*)&bi[lane * 8 + 4];
    float o[8];
    o[0] = (x[0] - mean) * rstd * s0.x + b0.x;  o[1] = (x[1] - mean) * rstd * s0.y + b0.y;
    o[2] = (x[2] - mean) * rstd * s0.z + b0.z;  o[3] = (x[3] - mean) * rstd * s0.w + b0.w;
    o[4] = (x[4] - mean) * rstd * s1.x + b1.x;  o[5] = (x[5] - mean) * rstd * s1.y + b1.y;
    o[6] = (x[6] - mean) * rstd * s1.z + b1.z;  o[7] = (x[7] - mean) * rstd * s1.w + b1.w;
    if (FOUT) {
        float4 w0 = {o[0], o[1], o[2], o[3]}, w1 = {o[4], o[5], o[6], o[7]};
        *(float4*)&fout[base] = w0;
        *(float4*)&fout[base + 4] = w1;
    } else {
        uint4 pk = {pack2(o[0], o[1]), pack2(o[2], o[3]), pack2(o[4], o[5]), pack2(o[6], o[7])};
        *(uint4*)&hb[base] = pk;
    }
}

// ---------------- host launch ----------------
extern "C" void kernel_launch(void* const* d_in, const int* in_sizes, int n_in,
                              void* d_out, int out_size, void* d_ws, size_t ws_size,
                              hipStream_t stream) {
    const float* x     = (const float*)d_in[0];
    const float* Wemb  = (const float*)d_in[1];
    const float* bemb  = (const float*)d_in[2];
    const float* Wq    = (const float*)d_in[3];
    const float* bq    = (const float*)d_in[4];
    const float* Wk    = (const float*)d_in[5];
    const float* bk    = (const float*)d_in[6];
    const float* Wv    = (const float*)d_in[7];
    const float* bv    = (const float*)d_in[8];
    const float* Wo    = (const float*)d_in[9];
    const float* bo    = (const float*)d_in[10];
    const float* ln1s  = (const float*)d_in[11];
    const float* ln1b  = (const float*)d_in[12];
    const float* W1    = (const float*)d_in[13];
    const float* b1    = (const float*)d_in[14];
    const float* W2    = (const float*)d_in[15];
    const float* b2    = (const float*)d_in[16];
    const float* ln2s  = (const float*)d_in[17];
    const float* ln2b  = (const float*)d_in[18];

    char* p = (char*)d_ws;
    auto carve = [&](size_t bytes) { char* r = p; p += (bytes + 255) & ~(size_t)255; return r; };

    unsigned short* wt_emb = (unsigned short*)carve((size_t)DM * DIN * 2);
    unsigned short* wt_qkv = (unsigned short*)carve((size_t)NL * 3 * DM * DM * 2);
    unsigned short* wt_o   = (unsigned short*)carve((size_t)NL * DM * DM * 2);
    unsigned short* wt_1   = (unsigned short*)carve((size_t)NL * DF * DM * 2);
    unsigned short* wt_2   = (unsigned short*)carve((size_t)NL * DM * DF * 2);
    float*          biasq  = (float*)carve((size_t)NL * 3 * DM * 4);
    float*          pe     = (float*)carve((size_t)SEQ * DM * 4);
    unsigned short* xb     = (unsigned short*)carve((size_t)MPAD * DIN * 2);
    unsigned short* h      = (unsigned short*)carve((size_t)MPAD * DM * 2);
    unsigned short* ob     = (unsigned short*)carve((size_t)MPAD * DM * 2);
    unsigned short* t0b    = (unsigned short*)carve((size_t)MPAD * DM * 2);
    unsigned short* t0c    = (unsigned short*)carve((size_t)MPAD * DM * 2);   // split-K partial
    unsigned short* vT     = (unsigned short*)carve((size_t)BATCH * NH * 64 * 512 * 2 + 1024);
    unsigned short* qkv    = (unsigned short*)carve((size_t)MPAD * DF * 2);
    unsigned short* f1     = qkv;

    dim3 blk256(256);

    // ALL weight transposes in one launch (6272 tiles)
    wprep_k<<<dim3(6272), dim3(32, 8), 0, stream>>>(Wemb, Wq, Wk, Wv, Wo, W1, W2,
                                                    wt_emb, wt_qkv, wt_o, wt_1, wt_2);
    prep_k<<<dim3((SEQ * DM + 255) / 256), blk256, 0, stream>>>(bq, bk, bv, biasq, pe);
    xcast_k<<<dim3(ROWS * DIN / 4 / 256), blk256, 0, stream>>>(x, xb, ROWS * DIN);

    const int Mt256 = MPAD / 256;   // 63
    const int Mt128 = MPAD / 128;   // 126

    // embedding + posenc -> bf16 h (gemm2, MODE 3)
    gemm2_k<128, 128, 3><<<dim3(Mt128 * 4), blk256, 0, stream>>>(
        xb, wt_emb, bemb, h, pe, Mt128, 4, DIN, DM);

    for (int l = 0; l < NL; ++l) {
        // QKV (gemm2, 1512 blocks, 3 blk/CU)
        gemm2_k<128, 128, 1><<<dim3(Mt128 * 12), blk256, 0, stream>>>(
            h, wt_qkv + (size_t)l * 3 * DM * DM, biasq + (size_t)l * 3 * DM,
            qkv, nullptr, Mt128, 12, DM, 3 * DM);
        // V transpose
        vtrans_k<<<dim3(16, BATCH * NH), blk256, 0, stream>>>(qkv, vT);
        // attention
        attn_k<<<dim3(BATCH * NH * NIB), blk256, 0, stream>>>(qkv, vT, ob);
        // O-proj: gemm3 split-K=2 (raw partials -> t0b, t0c; bias bo added in LN1)
        gemm3_k<0><<<dim3(Mt256 * 2 * 2), dim3(512), 0, stream>>>(
            ob, wt_o + (size_t)l * DM * DM, nullptr,
            t0b, t0c, Mt256, 2, 256, DM, DM);
        // LN1: h = LN(h + t0b + t0c + bo)
        ln_k<0><<<dim3(ROWS / 4), blk256, 0, stream>>>(
            h, t0b, t0c, bo + (size_t)l * DM,
            ln1s + (size_t)l * DM, ln1b + (size_t)l * DM, h, nullptr);
        // FFN1 -> f1 (relu, +bias): gemm3 full-K
        gemm3_k<2><<<dim3(Mt256 * 8), dim3(512), 0, stream>>>(
            h, wt_1 + (size_t)l * DF * DM, b1 + (size_t)l * DF,
            f1, nullptr, Mt256, 8, DM, DM, DF);
        // FFN2: gemm3 split-K=2 (raw partials; bias b2 added in LN2)
        gemm3_k<0><<<dim3(Mt256 * 2 * 2), dim3(512), 0, stream>>>(
            f1, wt_2 + (size_t)l * DM * DF, nullptr,
            t0b, t0c, Mt256, 2, 1024, DF, DM);
        // LN2: h = LN(h + t0b + t0c + b2) ; final layer writes f32 d_out
        if (l == NL - 1)
            ln_k<1><<<dim3(ROWS / 4), blk256, 0, stream>>>(
                h, t0b, t0c, b2 + (size_t)l * DM,
                ln2s + (size_t)l * DM, ln2b + (size_t)l * DM, nullptr, (float*)d_out);
        else
            ln_k<0><<<dim3(ROWS / 4), blk256, 0, stream>>>(
                h, t0b, t0c, b2 + (size_t)l * DM,
                ln2s + (size_t)l * DM, ln2b + (size_t)l * DM, h, nullptr);
    }
}